// Round 5
// baseline (1251.572 us; speedup 1.0000x reference)
//
#include <hip/hip_runtime.h>
#include <hip/hip_bf16.h>
#include <math.h>

#define NODE_DIM  64
#define EDGE_DIM  32
#define NUM_GAUSS 16
#define HIDDEN    128
#define CAT_DIM   160
#define TE        128                   // edges per block in edge kernel
#define ES        136                   // eac LDS row stride (shorts)
#define L1ABSZ    (64 * 256)            // packed W1ab per layer (K=64, N=256)
#define L1CSZ     (32 * 128)            // packed W1c per layer  (K=32, N=128)
#define L2SZ      (HIDDEN * NODE_DIM)   // packed W2 per layer   (K=128, N=64)

typedef __attribute__((ext_vector_type(8))) short short8;
typedef __attribute__((ext_vector_type(4))) float float4v;

static __device__ __forceinline__ short f2bf(float x) {
  __hip_bfloat16 h = __float2bfloat16(x);
  return *reinterpret_cast<short*>(&h);
}
static __device__ __forceinline__ float bflo(unsigned u) { return __uint_as_float(u << 16); }
static __device__ __forceinline__ float bfhi(unsigned u) { return __uint_as_float(u & 0xffff0000u); }

// ---------------- init: h_f32 = embed[atoms], h_bf16 mirror ----------------
__global__ void k_init(const int* __restrict__ atoms, const float* __restrict__ embed_w,
                       float* __restrict__ hf, short* __restrict__ hb, int n) {
  int stride = gridDim.x * blockDim.x;
  for (int i = blockIdx.x * blockDim.x + threadIdx.x; i < n; i += stride) {
    float f = embed_w[atoms[i >> 6] * NODE_DIM + (i & 63)];
    hf[i] = f;
    hb[i] = f2bf(f);
  }
}

__global__ void k_zero_f(float* __restrict__ p, int n) {
  int stride = gridDim.x * blockDim.x;
  for (int i = blockIdx.x * blockDim.x + threadIdx.x; i < n; i += stride) p[i] = 0.f;
}
__global__ void k_zero_i(int* __restrict__ p, int n) {
  int i = blockIdx.x * blockDim.x + threadIdx.x;
  if (i < n) p[i] = 0;
}
__global__ void k_zero4(float4* __restrict__ p, int n4) {
  int stride = gridDim.x * blockDim.x;
  for (int i = blockIdx.x * blockDim.x + threadIdx.x; i < n4; i += stride)
    p[i] = make_float4(0.f, 0.f, 0.f, 0.f);
}

// ---------------- edge precompute: distk = (+/-)dist, sign encodes kind ----------------
__global__ void k_edge_pre(const int* __restrict__ src, const int* __restrict__ dst,
                           const float* __restrict__ coords, const int* __restrict__ isr,
                           float* __restrict__ distk, int E) {
  int stride = gridDim.x * blockDim.x;
  for (int e = blockIdx.x * blockDim.x + threadIdx.x; e < E; e += stride) {
    int s = src[e], d = dst[e];
    float dx = coords[s*3+0] - coords[d*3+0];
    float dy = coords[s*3+1] - coords[d*3+1];
    float dz = coords[s*3+2] - coords[d*3+2];
    float dist = sqrtf(dx*dx + dy*dy + dz*dz);
    distk[e] = (isr[s] != isr[d]) ? -dist : dist;
  }
}

// ---------------- CSR-order build ----------------
__global__ void k_hist(const int* __restrict__ dst, int* __restrict__ counts, int E) {
  int stride = gridDim.x * blockDim.x;
  for (int e = blockIdx.x * blockDim.x + threadIdx.x; e < E; e += stride)
    atomicAdd(&counts[dst[e]], 1);
}

__global__ void k_scan(const int* __restrict__ counts, int* __restrict__ cursor, int N) {
  __shared__ int part[1024];
  int t = threadIdx.x;
  int chunk = (N + 1023) / 1024;
  int b = t * chunk, e = min(b + chunk, N);
  int s = 0;
  for (int i = b; i < e; ++i) s += counts[i];
  part[t] = s;
  __syncthreads();
  for (int o = 1; o < 1024; o <<= 1) {
    int v = (t >= o) ? part[t - o] : 0;
    __syncthreads();
    part[t] += v;
    __syncthreads();
  }
  int run = part[t] - s;
  for (int i = b; i < e; ++i) { cursor[i] = run; run += counts[i]; }
}

__global__ void k_build(const int* __restrict__ src, const int* __restrict__ dst,
                        const float* __restrict__ distk, int* __restrict__ cursor,
                        int* __restrict__ se_p, int* __restrict__ de_p,
                        float* __restrict__ dk_p, int E) {
  int stride = gridDim.x * blockDim.x;
  for (int e = blockIdx.x * blockDim.x + threadIdx.x; e < E; e += stride) {
    int d = dst[e];
    int p = atomicAdd(&cursor[d], 1);
    se_p[p] = src[e];
    de_p[p] = d;
    dk_p[p] = distk[e];
  }
}

// ---------------- weight packing (B-fragment order: ((kt*4+quad)*N + n)*8 + j) ----------------
// W1ab: K=64 (h dims), N=256 ([pa cols | pb cols]); pa from W1 rows 0..63, pb rows 64..127
__global__ void k_pack_w1ab(const float* __restrict__ W1, short* __restrict__ Wp, int total) {
  int i = blockIdx.x * blockDim.x + threadIdx.x;
  if (i >= total) return;
  int l = i / L1ABSZ, r = i % L1ABSZ;
  int k = r / 256, n = r % 256;
  int kt = k >> 5, quad = (k >> 3) & 3, j = k & 7;
  int srow = (n < 128) ? k : 64 + k;
  int scol = (n < 128) ? n : n - 128;
  Wp[l * L1ABSZ + ((kt*4 + quad) * 256 + n) * 8 + j] =
      f2bf(W1[(size_t)l * CAT_DIM * HIDDEN + srow * HIDDEN + scol]);
}
// W1c: K=32 (edge-attr dims = W1 rows 128..159), N=128
__global__ void k_pack_w1c(const float* __restrict__ W1, short* __restrict__ Wp, int total) {
  int i = blockIdx.x * blockDim.x + threadIdx.x;
  if (i >= total) return;
  int l = i / L1CSZ, r = i % L1CSZ;
  int k = r / 128, n = r % 128;
  int quad = k >> 3, j = k & 7;
  Wp[l * L1CSZ + (quad * 128 + n) * 8 + j] =
      f2bf(W1[(size_t)l * CAT_DIM * HIDDEN + (128 + k) * HIDDEN + n]);
}
// W2: K=128, N=64
__global__ void k_pack_w2(const float* __restrict__ W, short* __restrict__ Wp, int total) {
  int i = blockIdx.x * blockDim.x + threadIdx.x;
  if (i >= total) return;
  int l = i / L2SZ, r = i % L2SZ;
  int k = r / NODE_DIM, n = r % NODE_DIM;
  int kt = k >> 5, quad = (k >> 3) & 3, j = k & 7;
  Wp[l * L2SZ + ((kt*4 + quad) * NODE_DIM + n) * 8 + j] = f2bf(W[i]);
}

// ---------------- node kernel: [agg=S@W2+cnt*b2; h=relu(h+agg); S=0] ; [pa|pb = h@W1ab] ----------------
// 4 waves x 16 rows = 64 nodes/block; wave-private LDS h tile; barrier-free.
__global__ __launch_bounds__(256, 2) void k_node(
    float* __restrict__ hf, const short* __restrict__ hb,
    float* __restrict__ S, const int* __restrict__ cnts,
    const short* __restrict__ W2p, const float* __restrict__ b2,
    const short* __restrict__ W1abp, const float* __restrict__ b1,
    short* __restrict__ pa, short* __restrict__ pb, int N)
{
  __shared__ short ht[64 * 72];   // h tile bf16, stride 72

  const int tid  = threadIdx.x;
  const int lane = tid & 63;
  const int w    = tid >> 6;
  const int quad = lane >> 4;
  const int l16  = lane & 15;
  const int base = blockIdx.x * 64 + w * 16;

  if (W2p) {
    // ---- phase A: aggregate GEMM + relu residual ----
    float4v acc[4];
    #pragma unroll
    for (int nt = 0; nt < 4; ++nt) acc[nt] = (float4v)0.f;
    const int arow = base + l16;
    const bool av = arow < N;
    #pragma unroll
    for (int kt = 0; kt < 4; ++kt) {
      short8 a;
      if (av) {
        const float* sp = &S[(size_t)arow * 128 + kt*32 + quad*8];
        float4 x0 = *(const float4*)sp;
        float4 x1 = *(const float4*)(sp + 4);
        a[0]=f2bf(x0.x); a[1]=f2bf(x0.y); a[2]=f2bf(x0.z); a[3]=f2bf(x0.w);
        a[4]=f2bf(x1.x); a[5]=f2bf(x1.y); a[6]=f2bf(x1.z); a[7]=f2bf(x1.w);
      } else a = (short8)0;
      #pragma unroll
      for (int nt = 0; nt < 4; ++nt) {
        short8 b = *(const short8*)&W2p[((kt*4 + quad) * NODE_DIM + nt*16 + l16) * 8];
        acc[nt] = __builtin_amdgcn_mfma_f32_16x16x32_bf16(a, b, acc[nt], 0, 0, 0);
      }
    }
    // re-zero S for next layer
    if (av) {
      float4 z = make_float4(0.f, 0.f, 0.f, 0.f);
      #pragma unroll
      for (int kt = 0; kt < 4; ++kt) {
        float* sp = &S[(size_t)arow * 128 + kt*32 + quad*8];
        *(float4*)sp = z; *(float4*)(sp + 4) = z;
      }
    }
    float cf[4];
    #pragma unroll
    for (int r = 0; r < 4; ++r) {
      int row = base + quad*4 + r;
      cf[r] = (row < N) ? (float)cnts[row] : 0.f;
    }
    #pragma unroll
    for (int nt = 0; nt < 4; ++nt) {
      int col = nt*16 + l16;
      float bb = b2[col];
      #pragma unroll
      for (int r = 0; r < 4; ++r) {
        int row = base + quad*4 + r;
        int lrow = w*16 + quad*4 + r;
        if (row < N) {
          float v = hf[(size_t)row * 64 + col] + acc[nt][r] + cf[r] * bb;
          v = fmaxf(v, 0.f);
          hf[(size_t)row * 64 + col] = v;
          ht[lrow * 72 + col] = f2bf(v);
        } else {
          ht[lrow * 72 + col] = 0;
        }
      }
    }
  } else {
    // ---- first layer: stage hb -> ht (wave-private rows) ----
    int row = base + l16;
    #pragma unroll
    for (int c = 0; c < 2; ++c) {
      int colc = quad*16 + c*8;
      short8 v = (row < N) ? *(const short8*)&hb[(size_t)row * 64 + colc] : (short8)0;
      *(short8*)&ht[(w*16 + l16) * 72 + colc] = v;
    }
  }

  if (W1abp) {
    // ---- phase B: [pa|pb] = h @ W1ab (+b1 on pa cols) ----
    float4v acc[16];
    #pragma unroll
    for (int nt = 0; nt < 16; ++nt) acc[nt] = (float4v)0.f;
    #pragma unroll
    for (int kt = 0; kt < 2; ++kt) {
      short8 a = *(const short8*)&ht[(w*16 + l16) * 72 + kt*32 + quad*8];
      #pragma unroll
      for (int nt = 0; nt < 16; ++nt) {
        short8 b = *(const short8*)&W1abp[((kt*4 + quad) * 256 + nt*16 + l16) * 8];
        acc[nt] = __builtin_amdgcn_mfma_f32_16x16x32_bf16(a, b, acc[nt], 0, 0, 0);
      }
    }
    #pragma unroll
    for (int nt = 0; nt < 16; ++nt) {
      int col = nt*16 + l16;                       // 0..255
      float bb = (col < 128) ? b1[col] : 0.f;
      #pragma unroll
      for (int r = 0; r < 4; ++r) {
        int row = base + quad*4 + r;
        if (row < N) {
          float v = acc[nt][r] + bb;
          if (col < 128) pa[(size_t)row * 128 + col]         = f2bf(v);
          else           pb[(size_t)row * 128 + (col - 128)] = f2bf(v);
        }
      }
    }
  }
}

// ---------------- edge kernel: eac MFMA + gather/silu/segmented-sum into S ----------------
__global__ __launch_bounds__(256, 4) void k_edge(
    const short* __restrict__ pa, const short* __restrict__ pb,
    const int* __restrict__ se_p, const int* __restrict__ de_p,
    const float* __restrict__ dk_p, const float* __restrict__ sub_w,
    const short* __restrict__ W1cp,
    float* __restrict__ S, int E)
{
  __shared__ short eac[TE * ES];     // 34816 B, wave-private 32-row strips
  __shared__ int   ses[TE], des[TE];
  __shared__ float dks[TE];

  const int tid  = threadIdx.x;
  const int lane = tid & 63;
  const int w    = tid >> 6;
  const int quad = lane >> 4;
  const int l16  = lane & 15;
  const int ebase = blockIdx.x * TE;

  if (tid < TE) {
    int ge = ebase + tid;
    bool v = ge < E;
    ses[tid] = v ? se_p[ge] : 0;
    des[tid] = v ? de_p[ge] : -1;
    dks[tid] = v ? dk_p[ge] : 0.f;
  }
  __syncthreads();

  // ---- phase 1: eac = ea @ W1c for rows [w*32, w*32+32) ----
  {
    const int c0 = quad * 8;
    short8 ea[2];
    #pragma unroll
    for (int mt = 0; mt < 2; ++mt) {
      float dk = dks[w*32 + mt*16 + l16];
      if (quad < 2) {
        float dist = fabsf(dk);
        #pragma unroll
        for (int j = 0; j < 8; ++j) {
          float t = dist - (float)(c0 + j) * (1.0f / 3.0f);
          ea[mt][j] = f2bf(__expf(-4.5f * t * t));
        }
      } else {
        int kk = (int)(__float_as_uint(dk) >> 31);
        const float* sw = &sub_w[kk * NUM_GAUSS + (c0 - 16)];
        #pragma unroll
        for (int j = 0; j < 8; ++j) ea[mt][j] = f2bf(sw[j]);
      }
    }
    float4v acc[2][8];
    #pragma unroll
    for (int mt = 0; mt < 2; ++mt)
      #pragma unroll
      for (int nt = 0; nt < 8; ++nt) acc[mt][nt] = (float4v)0.f;
    #pragma unroll
    for (int nt = 0; nt < 8; ++nt) {
      short8 b = *(const short8*)&W1cp[(quad * 128 + nt*16 + l16) * 8];
      acc[0][nt] = __builtin_amdgcn_mfma_f32_16x16x32_bf16(ea[0], b, acc[0][nt], 0, 0, 0);
      acc[1][nt] = __builtin_amdgcn_mfma_f32_16x16x32_bf16(ea[1], b, acc[1][nt], 0, 0, 0);
    }
    #pragma unroll
    for (int mt = 0; mt < 2; ++mt)
      #pragma unroll
      for (int nt = 0; nt < 8; ++nt)
        #pragma unroll
        for (int r = 0; r < 4; ++r)
          eac[(w*32 + mt*16 + quad*4 + r) * ES + nt*16 + l16] = f2bf(acc[mt][nt][r]);
  }
  // wave-private rows: same wave consumes below; in-order LDS, no barrier

  // ---- phase 2: per-edge assembly + silu + run-length segmented sum ----
  {
    const int d2 = lane * 2;
    int prev_d = (w > 0) ? des[w*32 - 1] : ((ebase > 0) ? de_p[ebase - 1] : -1);
    int next_d = (w < 3) ? des[w*32 + 32] : ((ebase + TE < E) ? de_p[ebase + TE] : -1);

    int   cur = -2;
    float s0 = 0.f, s1 = 0.f;
    float p0 = 0.f, p1 = 0.f;
    bool  openL = false;

    #pragma unroll 4
    for (int i = 0; i < 32; ++i) {
      int row = w*32 + i;
      int d = des[row];
      if (d != cur) {
        if (cur >= 0) {
          if (openL) {
            atomicAdd(&S[(size_t)cur * 128 + d2],     s0);
            atomicAdd(&S[(size_t)cur * 128 + d2 + 1], s1);
          } else {
            *(float2*)&S[(size_t)cur * 128 + d2] = make_float2(s0, s1);
          }
        }
        cur = d; s0 = 0.f; s1 = 0.f;
        openL = (i == 0) && (prev_d == d);
        if (d >= 0) {
          unsigned u = *(const unsigned*)&pa[(size_t)d * 128 + d2];
          p0 = bflo(u); p1 = bfhi(u);
        }
      }
      if (cur >= 0) {
        int se = ses[row];
        unsigned ub = *(const unsigned*)&pb[(size_t)se * 128 + d2];
        unsigned ue = *(const unsigned*)&eac[row * ES + d2];
        float x0 = p0 + bflo(ub) + bflo(ue);
        float x1 = p1 + bfhi(ub) + bfhi(ue);
        s0 += x0 * __builtin_amdgcn_rcpf(1.f + __expf(-x0));
        s1 += x1 * __builtin_amdgcn_rcpf(1.f + __expf(-x1));
      }
    }
    if (cur >= 0) {
      bool openR = (next_d == cur);
      if (openL || openR) {
        atomicAdd(&S[(size_t)cur * 128 + d2],     s0);
        atomicAdd(&S[(size_t)cur * 128 + d2 + 1], s1);
      } else {
        *(float2*)&S[(size_t)cur * 128 + d2] = make_float2(s0, s1);
      }
    }
  }
}

// ---------------- mean pool (batch_ids sorted): wave per 64 nodes ----------------
__global__ void k_pool(const float* __restrict__ h, const int* __restrict__ batch_ids,
                       float* __restrict__ pooled, float* __restrict__ counts, int N) {
  int lane = threadIdx.x & 63;
  int base = blockIdx.x * 64;
  float acc = 0.f;
  int   cnt = 0;
  int  gcur = -1;
  for (int n = 0; n < 64; ++n) {
    int node = base + n;
    if (node >= N) break;
    int g = batch_ids[node];
    if (g != gcur) {
      if (gcur >= 0) {
        atomicAdd(&pooled[gcur * NODE_DIM + lane], acc);
        if (lane == 0) atomicAdd(&counts[gcur], (float)cnt);
      }
      gcur = g; acc = 0.f; cnt = 0;
    }
    acc += h[(size_t)node * NODE_DIM + lane];
    cnt++;
  }
  if (gcur >= 0) {
    atomicAdd(&pooled[gcur * NODE_DIM + lane], acc);
    if (lane == 0) atomicAdd(&counts[gcur], (float)cnt);
  }
}

__global__ void k_final(const float* __restrict__ pooled, const float* __restrict__ counts,
                        const float* __restrict__ fc_w, const float* __restrict__ fc_b,
                        float* __restrict__ out, int G) {
  int g = blockIdx.x * blockDim.x + threadIdx.x;
  if (g < G) {
    float acc = 0.f;
    for (int d = 0; d < NODE_DIM; ++d) acc += pooled[g * NODE_DIM + d] * fc_w[d];
    float c = counts[g];
    if (c < 1.f) c = 1.f;
    out[g] = acc / c + fc_b[0];
  }
}

extern "C" void kernel_launch(void* const* d_in, const int* in_sizes, int n_in,
                              void* d_out, int out_size, void* d_ws, size_t ws_size,
                              hipStream_t stream) {
  const int*   atoms   = (const int*)  d_in[0];
  const int*   eidx    = (const int*)  d_in[1];
  const float* coords  = (const float*)d_in[2];
  const int*   isr     = (const int*)  d_in[3];
  const int*   batch   = (const int*)  d_in[4];
  const float* embed_w = (const float*)d_in[5];
  const float* sub_w   = (const float*)d_in[6];
  const float* W1      = (const float*)d_in[7];
  const float* b1      = (const float*)d_in[8];
  const float* W2      = (const float*)d_in[9];
  const float* b2      = (const float*)d_in[10];
  const float* fc_w    = (const float*)d_in[11];
  const float* fc_b    = (const float*)d_in[12];
  float* out = (float*)d_out;

  const int N = in_sizes[0];
  const int E = in_sizes[1] / 2;
  const int L = in_sizes[8] / HIDDEN;
  const int G = out_size;

  const int* srcv = eidx;
  const int* dstv = eidx + E;

  size_t off = 0;
  auto carve = [&](size_t bytes) -> char* {
    char* p = (char*)d_ws + off;
    off += (bytes + 255) & ~(size_t)255;
    return p;
  };
  float* hf     = (float*)carve((size_t)N * NODE_DIM * 4);
  short* hb     = (short*)carve((size_t)N * NODE_DIM * 2);
  float* S      = (float*)carve((size_t)N * HIDDEN * 4);
  short* pa     = (short*)carve((size_t)N * HIDDEN * 2);
  short* pb     = (short*)carve((size_t)N * HIDDEN * 2);
  float* distk  = (float*)carve((size_t)E * 4);
  int*   cnts   = (int*)  carve((size_t)N * 4);
  int*   cursor = (int*)  carve((size_t)N * 4);
  int*   se_p   = (int*)  carve((size_t)E * 4);
  int*   de_p   = (int*)  carve((size_t)E * 4);
  float* dk_p   = (float*)carve((size_t)E * 4);
  short* W1abp  = (short*)carve((size_t)L * L1ABSZ * 2);
  short* W1cp   = (short*)carve((size_t)L * L1CSZ * 2);
  short* W2p    = (short*)carve((size_t)L * L2SZ * 2);
  float* pooled = (float*)carve((size_t)G * NODE_DIM * 4);
  float* cntg   = (float*)carve((size_t)G * 4);

  k_init<<<1024, 256, 0, stream>>>(atoms, embed_w, hf, hb, N * NODE_DIM);
  k_zero4<<<2048, 256, 0, stream>>>((float4*)S, N * HIDDEN / 4);
  k_edge_pre<<<1024, 256, 0, stream>>>(srcv, dstv, coords, isr, distk, E);
  k_zero_i<<<(N + 255) / 256, 256, 0, stream>>>(cnts, N);
  k_zero_f<<<(G * NODE_DIM + G + 255) / 256, 256, 0, stream>>>(pooled, G * NODE_DIM + G);
  k_hist<<<1024, 256, 0, stream>>>(dstv, cnts, E);
  k_scan<<<1, 1024, 0, stream>>>(cnts, cursor, N);
  k_build<<<1024, 256, 0, stream>>>(srcv, dstv, distk, cursor, se_p, de_p, dk_p, E);
  k_pack_w1ab<<<(L * L1ABSZ + 255) / 256, 256, 0, stream>>>(W1, W1abp, L * L1ABSZ);
  k_pack_w1c<<<(L * L1CSZ + 255) / 256, 256, 0, stream>>>(W1, W1cp, L * L1CSZ);
  k_pack_w2<<<(L * L2SZ + 255) / 256, 256, 0, stream>>>(W2, W2p, L * L2SZ);

  const int nblk_n = (N + 63) / 64;
  const int nblk_e = (E + TE - 1) / TE;
  for (int l = 0; l < L; ++l) {
    k_node<<<nblk_n, 256, 0, stream>>>(
        hf, hb, S, cnts,
        (l > 0) ? W2p + (size_t)(l - 1) * L2SZ : (const short*)nullptr,
        (l > 0) ? b2 + (size_t)(l - 1) * NODE_DIM : (const float*)nullptr,
        W1abp + (size_t)l * L1ABSZ, b1 + (size_t)l * HIDDEN,
        pa, pb, N);
    k_edge<<<nblk_e, 256, 0, stream>>>(pa, pb, se_p, de_p, dk_p, sub_w,
                                       W1cp + (size_t)l * L1CSZ, S, E);
  }
  k_node<<<nblk_n, 256, 0, stream>>>(
      hf, hb, S, cnts,
      W2p + (size_t)(L - 1) * L2SZ, b2 + (size_t)(L - 1) * NODE_DIM,
      (const short*)nullptr, (const float*)nullptr, pa, pb, N);

  k_pool<<<(N + 63) / 64, 64, 0, stream>>>(hf, batch, pooled, cntg, N);
  k_final<<<1, 64, 0, stream>>>(pooled, cntg, fc_w, fc_b, out, G);
}

// Round 6
// 842.632 us; speedup vs baseline: 1.4853x; 1.4853x over previous
//
#include <hip/hip_runtime.h>
#include <hip/hip_bf16.h>
#include <math.h>

#define NODE_DIM  64
#define EDGE_DIM  32
#define NUM_GAUSS 16
#define HIDDEN    128
#define CAT_DIM   160
#define TE        128                   // edges per block in edge kernel
#define ES        136                   // eac LDS row stride (shorts)
#define L1ABSZ    (64 * 256)            // packed W1ab per layer (K=64, N=256)
#define L1CSZ     (32 * 128)            // packed W1c per layer  (K=32, N=128)
#define L2SZ      (HIDDEN * NODE_DIM)   // packed W2 per layer   (K=128, N=64)

typedef __attribute__((ext_vector_type(8))) short short8;
typedef __attribute__((ext_vector_type(4))) float float4v;

static __device__ __forceinline__ short f2bf(float x) {
  __hip_bfloat16 h = __float2bfloat16(x);
  return *reinterpret_cast<short*>(&h);
}
static __device__ __forceinline__ float bflo(unsigned u) { return __uint_as_float(u << 16); }
static __device__ __forceinline__ float bfhi(unsigned u) { return __uint_as_float(u & 0xffff0000u); }

// ---------------- init: h_f32 = embed[atoms], h_bf16 mirror ----------------
__global__ void k_init(const int* __restrict__ atoms, const float* __restrict__ embed_w,
                       float* __restrict__ hf, short* __restrict__ hb, int n) {
  int stride = gridDim.x * blockDim.x;
  for (int i = blockIdx.x * blockDim.x + threadIdx.x; i < n; i += stride) {
    float f = embed_w[atoms[i >> 6] * NODE_DIM + (i & 63)];
    hf[i] = f;
    hb[i] = f2bf(f);
  }
}

__global__ void k_zero_f(float* __restrict__ p, int n) {
  int stride = gridDim.x * blockDim.x;
  for (int i = blockIdx.x * blockDim.x + threadIdx.x; i < n; i += stride) p[i] = 0.f;
}
__global__ void k_zero_i(int* __restrict__ p, int n) {
  int i = blockIdx.x * blockDim.x + threadIdx.x;
  if (i < n) p[i] = 0;
}
__global__ void k_zero4(float4* __restrict__ p, int n4) {
  int stride = gridDim.x * blockDim.x;
  for (int i = blockIdx.x * blockDim.x + threadIdx.x; i < n4; i += stride)
    p[i] = make_float4(0.f, 0.f, 0.f, 0.f);
}

// ---------------- edge precompute: distk = (+/-)dist, sign encodes kind ----------------
__global__ void k_edge_pre(const int* __restrict__ src, const int* __restrict__ dst,
                           const float* __restrict__ coords, const int* __restrict__ isr,
                           float* __restrict__ distk, int E) {
  int stride = gridDim.x * blockDim.x;
  for (int e = blockIdx.x * blockDim.x + threadIdx.x; e < E; e += stride) {
    int s = src[e], d = dst[e];
    float dx = coords[s*3+0] - coords[d*3+0];
    float dy = coords[s*3+1] - coords[d*3+1];
    float dz = coords[s*3+2] - coords[d*3+2];
    float dist = sqrtf(dx*dx + dy*dy + dz*dz);
    distk[e] = (isr[s] != isr[d]) ? -dist : dist;
  }
}

// ---------------- CSR-order build ----------------
__global__ void k_hist(const int* __restrict__ dst, int* __restrict__ counts, int E) {
  int stride = gridDim.x * blockDim.x;
  for (int e = blockIdx.x * blockDim.x + threadIdx.x; e < E; e += stride)
    atomicAdd(&counts[dst[e]], 1);
}

// hierarchical exclusive scan: partials -> top scan -> apply
__global__ void k_scan_part(const int* __restrict__ counts, int* __restrict__ part, int N) {
  __shared__ int red[256];
  int t = threadIdx.x;
  int i = blockIdx.x * 256 + t;
  red[t] = (i < N) ? counts[i] : 0;
  __syncthreads();
  for (int o = 128; o > 0; o >>= 1) {
    if (t < o) red[t] += red[t + o];
    __syncthreads();
  }
  if (t == 0) part[blockIdx.x] = red[0];
}

__global__ void k_scan_top(int* __restrict__ part, int nb) {
  __shared__ int s[512];
  int t = threadIdx.x;
  int v = (t < nb) ? part[t] : 0;
  s[t] = v;
  __syncthreads();
  for (int o = 1; o < 512; o <<= 1) {
    int u = (t >= o) ? s[t - o] : 0;
    __syncthreads();
    s[t] += u;
    __syncthreads();
  }
  if (t < nb) part[t] = s[t] - v;   // exclusive
}

__global__ void k_scan_apply(const int* __restrict__ counts, const int* __restrict__ part,
                             int* __restrict__ cursor, int N) {
  __shared__ int s[256];
  int t = threadIdx.x;
  int i = blockIdx.x * 256 + t;
  int v = (i < N) ? counts[i] : 0;
  s[t] = v;
  __syncthreads();
  for (int o = 1; o < 256; o <<= 1) {
    int u = (t >= o) ? s[t - o] : 0;
    __syncthreads();
    s[t] += u;
    __syncthreads();
  }
  if (i < N) cursor[i] = part[blockIdx.x] + s[t] - v;   // exclusive
}

// scatter edges into dst-sorted order: (src, dist) as int2, de separate
__global__ void k_build(const int* __restrict__ src, const int* __restrict__ dst,
                        const float* __restrict__ distk, int* __restrict__ cursor,
                        int2* __restrict__ sd_p, int* __restrict__ de_p, int E) {
  int stride = gridDim.x * blockDim.x;
  for (int e = blockIdx.x * blockDim.x + threadIdx.x; e < E; e += stride) {
    int d = dst[e];
    int p = atomicAdd(&cursor[d], 1);
    sd_p[p] = make_int2(src[e], __float_as_int(distk[e]));
    de_p[p] = d;
  }
}

// ---------------- weight packing (B-fragment order: ((kt*4+quad)*N + n)*8 + j) ----------------
__global__ void k_pack_w1ab(const float* __restrict__ W1, short* __restrict__ Wp, int total) {
  int i = blockIdx.x * blockDim.x + threadIdx.x;
  if (i >= total) return;
  int l = i / L1ABSZ, r = i % L1ABSZ;
  int k = r / 256, n = r % 256;
  int kt = k >> 5, quad = (k >> 3) & 3, j = k & 7;
  int srow = (n < 128) ? k : 64 + k;
  int scol = (n < 128) ? n : n - 128;
  Wp[l * L1ABSZ + ((kt*4 + quad) * 256 + n) * 8 + j] =
      f2bf(W1[(size_t)l * CAT_DIM * HIDDEN + srow * HIDDEN + scol]);
}
__global__ void k_pack_w1c(const float* __restrict__ W1, short* __restrict__ Wp, int total) {
  int i = blockIdx.x * blockDim.x + threadIdx.x;
  if (i >= total) return;
  int l = i / L1CSZ, r = i % L1CSZ;
  int k = r / 128, n = r % 128;
  int quad = k >> 3, j = k & 7;
  Wp[l * L1CSZ + (quad * 128 + n) * 8 + j] =
      f2bf(W1[(size_t)l * CAT_DIM * HIDDEN + (128 + k) * HIDDEN + n]);
}
__global__ void k_pack_w2(const float* __restrict__ W, short* __restrict__ Wp, int total) {
  int i = blockIdx.x * blockDim.x + threadIdx.x;
  if (i >= total) return;
  int l = i / L2SZ, r = i % L2SZ;
  int k = r / NODE_DIM, n = r % NODE_DIM;
  int kt = k >> 5, quad = (k >> 3) & 3, j = k & 7;
  Wp[l * L2SZ + ((kt*4 + quad) * NODE_DIM + n) * 8 + j] = f2bf(W[i]);
}

// ---------------- node kernel: [agg=S@W2+cnt*b2; h=relu(h+agg); S=0] ; [pa|pb = h@W1ab] ----------------
__global__ __launch_bounds__(256, 2) void k_node(
    float* __restrict__ hf, const short* __restrict__ hb,
    float* __restrict__ S, const int* __restrict__ cnts,
    const short* __restrict__ W2p, const float* __restrict__ b2,
    const short* __restrict__ W1abp, const float* __restrict__ b1,
    short* __restrict__ pa, short* __restrict__ pb, int N)
{
  __shared__ short ht[64 * 72];

  const int tid  = threadIdx.x;
  const int lane = tid & 63;
  const int w    = tid >> 6;
  const int quad = lane >> 4;
  const int l16  = lane & 15;
  const int base = blockIdx.x * 64 + w * 16;

  if (W2p) {
    float4v acc[4];
    #pragma unroll
    for (int nt = 0; nt < 4; ++nt) acc[nt] = (float4v)0.f;
    const int arow = base + l16;
    const bool av = arow < N;
    #pragma unroll
    for (int kt = 0; kt < 4; ++kt) {
      short8 a;
      if (av) {
        const float* sp = &S[(size_t)arow * 128 + kt*32 + quad*8];
        float4 x0 = *(const float4*)sp;
        float4 x1 = *(const float4*)(sp + 4);
        a[0]=f2bf(x0.x); a[1]=f2bf(x0.y); a[2]=f2bf(x0.z); a[3]=f2bf(x0.w);
        a[4]=f2bf(x1.x); a[5]=f2bf(x1.y); a[6]=f2bf(x1.z); a[7]=f2bf(x1.w);
      } else a = (short8)0;
      #pragma unroll
      for (int nt = 0; nt < 4; ++nt) {
        short8 b = *(const short8*)&W2p[((kt*4 + quad) * NODE_DIM + nt*16 + l16) * 8];
        acc[nt] = __builtin_amdgcn_mfma_f32_16x16x32_bf16(a, b, acc[nt], 0, 0, 0);
      }
    }
    if (av) {
      float4 z = make_float4(0.f, 0.f, 0.f, 0.f);
      #pragma unroll
      for (int kt = 0; kt < 4; ++kt) {
        float* sp = &S[(size_t)arow * 128 + kt*32 + quad*8];
        *(float4*)sp = z; *(float4*)(sp + 4) = z;
      }
    }
    float cf[4];
    #pragma unroll
    for (int r = 0; r < 4; ++r) {
      int row = base + quad*4 + r;
      cf[r] = (row < N) ? (float)cnts[row] : 0.f;
    }
    #pragma unroll
    for (int nt = 0; nt < 4; ++nt) {
      int col = nt*16 + l16;
      float bb = b2[col];
      #pragma unroll
      for (int r = 0; r < 4; ++r) {
        int row = base + quad*4 + r;
        int lrow = w*16 + quad*4 + r;
        if (row < N) {
          float v = hf[(size_t)row * 64 + col] + acc[nt][r] + cf[r] * bb;
          v = fmaxf(v, 0.f);
          hf[(size_t)row * 64 + col] = v;
          ht[lrow * 72 + col] = f2bf(v);
        } else {
          ht[lrow * 72 + col] = 0;
        }
      }
    }
  } else {
    int row = base + l16;
    #pragma unroll
    for (int c = 0; c < 2; ++c) {
      int colc = quad*16 + c*8;
      short8 v = (row < N) ? *(const short8*)&hb[(size_t)row * 64 + colc] : (short8)0;
      *(short8*)&ht[(w*16 + l16) * 72 + colc] = v;
    }
  }

  if (W1abp) {
    float4v acc[16];
    #pragma unroll
    for (int nt = 0; nt < 16; ++nt) acc[nt] = (float4v)0.f;
    #pragma unroll
    for (int kt = 0; kt < 2; ++kt) {
      short8 a = *(const short8*)&ht[(w*16 + l16) * 72 + kt*32 + quad*8];
      #pragma unroll
      for (int nt = 0; nt < 16; ++nt) {
        short8 b = *(const short8*)&W1abp[((kt*4 + quad) * 256 + nt*16 + l16) * 8];
        acc[nt] = __builtin_amdgcn_mfma_f32_16x16x32_bf16(a, b, acc[nt], 0, 0, 0);
      }
    }
    #pragma unroll
    for (int nt = 0; nt < 16; ++nt) {
      int col = nt*16 + l16;
      float bb = (col < 128) ? b1[col] : 0.f;
      #pragma unroll
      for (int r = 0; r < 4; ++r) {
        int row = base + quad*4 + r;
        if (row < N) {
          float v = acc[nt][r] + bb;
          if (col < 128) pa[(size_t)row * 128 + col]         = f2bf(v);
          else           pb[(size_t)row * 128 + (col - 128)] = f2bf(v);
        }
      }
    }
  }
}

// ---------------- edge kernel: eac MFMA + batched gather/silu/segmented-sum ----------------
__global__ __launch_bounds__(256, 4) void k_edge(
    const short* __restrict__ pa, const short* __restrict__ pb,
    const int2* __restrict__ sd_p, const int* __restrict__ de_p,
    const float* __restrict__ sub_w,
    const short* __restrict__ W1cp,
    float* __restrict__ S, int E)
{
  __shared__ short eac[TE * ES];
  __shared__ int   ses[TE], des[TE];
  __shared__ float dks[TE];

  const int tid  = threadIdx.x;
  const int lane = tid & 63;
  const int w    = tid >> 6;
  const int quad = lane >> 4;
  const int l16  = lane & 15;
  const int ebase = blockIdx.x * TE;

  if (tid < TE) {
    int ge = ebase + tid;
    if (ge < E) {
      int2 v = sd_p[ge];
      ses[tid] = v.x;
      dks[tid] = __int_as_float(v.y);
      des[tid] = de_p[ge];
    } else {
      ses[tid] = 0; des[tid] = -1; dks[tid] = 0.f;
    }
  }
  __syncthreads();

  // ---- phase 1: eac = ea @ W1c for rows [w*32, w*32+32) ----
  {
    const int c0 = quad * 8;
    short8 ea[2];
    #pragma unroll
    for (int mt = 0; mt < 2; ++mt) {
      float dk = dks[w*32 + mt*16 + l16];
      if (quad < 2) {
        float dist = fabsf(dk);
        #pragma unroll
        for (int j = 0; j < 8; ++j) {
          float t = dist - (float)(c0 + j) * (1.0f / 3.0f);
          ea[mt][j] = f2bf(__expf(-4.5f * t * t));
        }
      } else {
        int kk = (int)(__float_as_uint(dk) >> 31);
        const float* sw = &sub_w[kk * NUM_GAUSS + (c0 - 16)];
        #pragma unroll
        for (int j = 0; j < 8; ++j) ea[mt][j] = f2bf(sw[j]);
      }
    }
    float4v acc[2][8];
    #pragma unroll
    for (int mt = 0; mt < 2; ++mt)
      #pragma unroll
      for (int nt = 0; nt < 8; ++nt) acc[mt][nt] = (float4v)0.f;
    #pragma unroll
    for (int nt = 0; nt < 8; ++nt) {
      short8 b = *(const short8*)&W1cp[(quad * 128 + nt*16 + l16) * 8];
      acc[0][nt] = __builtin_amdgcn_mfma_f32_16x16x32_bf16(ea[0], b, acc[0][nt], 0, 0, 0);
      acc[1][nt] = __builtin_amdgcn_mfma_f32_16x16x32_bf16(ea[1], b, acc[1][nt], 0, 0, 0);
    }
    #pragma unroll
    for (int mt = 0; mt < 2; ++mt)
      #pragma unroll
      for (int nt = 0; nt < 8; ++nt)
        #pragma unroll
        for (int r = 0; r < 4; ++r)
          eac[(w*32 + mt*16 + quad*4 + r) * ES + nt*16 + l16] = f2bf(acc[mt][nt][r]);
  }
  // wave-private rows: same wave consumes below; in-order LDS, no barrier

  // ---- phase 2: batched gathers (8 outstanding) + silu + run-length segmented sum ----
  {
    const int d2 = lane * 2;
    int prev_d = (w > 0) ? des[w*32 - 1] : ((ebase > 0) ? de_p[ebase - 1] : -1);
    int next_d = (w < 3) ? des[w*32 + 32] : ((ebase + TE < E) ? de_p[ebase + TE] : -1);

    int   cur = -2;
    float s0 = 0.f, s1 = 0.f;
    float p0 = 0.f, p1 = 0.f;
    bool  openL = false;

    for (int g = 0; g < 4; ++g) {
      const int rowb = w*32 + g*8;
      unsigned ub[8], ue[8];
      #pragma unroll
      for (int j = 0; j < 8; ++j)
        ub[j] = *(const unsigned*)&pb[(size_t)ses[rowb + j] * 128 + d2];
      #pragma unroll
      for (int j = 0; j < 8; ++j)
        ue[j] = *(const unsigned*)&eac[(rowb + j) * ES + d2];

      #pragma unroll
      for (int j = 0; j < 8; ++j) {
        int d = des[rowb + j];
        if (d != cur) {
          if (cur >= 0) {
            if (openL) {
              atomicAdd(&S[(size_t)cur * 128 + d2],     s0);
              atomicAdd(&S[(size_t)cur * 128 + d2 + 1], s1);
            } else {
              *(float2*)&S[(size_t)cur * 128 + d2] = make_float2(s0, s1);
            }
          }
          cur = d; s0 = 0.f; s1 = 0.f;
          openL = (g == 0) && (j == 0) && (prev_d == d);
          if (d >= 0) {
            unsigned u = *(const unsigned*)&pa[(size_t)d * 128 + d2];
            p0 = bflo(u); p1 = bfhi(u);
          }
        }
        if (cur >= 0) {
          float x0 = p0 + bflo(ub[j]) + bflo(ue[j]);
          float x1 = p1 + bfhi(ub[j]) + bfhi(ue[j]);
          s0 += x0 * __builtin_amdgcn_rcpf(1.f + __expf(-x0));
          s1 += x1 * __builtin_amdgcn_rcpf(1.f + __expf(-x1));
        }
      }
    }
    if (cur >= 0) {
      bool openR = (next_d == cur);
      if (openL || openR) {
        atomicAdd(&S[(size_t)cur * 128 + d2],     s0);
        atomicAdd(&S[(size_t)cur * 128 + d2 + 1], s1);
      } else {
        *(float2*)&S[(size_t)cur * 128 + d2] = make_float2(s0, s1);
      }
    }
  }
}

// ---------------- mean pool (batch_ids sorted): wave per 64 nodes ----------------
__global__ void k_pool(const float* __restrict__ h, const int* __restrict__ batch_ids,
                       float* __restrict__ pooled, float* __restrict__ counts, int N) {
  int lane = threadIdx.x & 63;
  int base = blockIdx.x * 64;
  float acc = 0.f;
  int   cnt = 0;
  int  gcur = -1;
  for (int n = 0; n < 64; ++n) {
    int node = base + n;
    if (node >= N) break;
    int g = batch_ids[node];
    if (g != gcur) {
      if (gcur >= 0) {
        atomicAdd(&pooled[gcur * NODE_DIM + lane], acc);
        if (lane == 0) atomicAdd(&counts[gcur], (float)cnt);
      }
      gcur = g; acc = 0.f; cnt = 0;
    }
    acc += h[(size_t)node * NODE_DIM + lane];
    cnt++;
  }
  if (gcur >= 0) {
    atomicAdd(&pooled[gcur * NODE_DIM + lane], acc);
    if (lane == 0) atomicAdd(&counts[gcur], (float)cnt);
  }
}

__global__ void k_final(const float* __restrict__ pooled, const float* __restrict__ counts,
                        const float* __restrict__ fc_w, const float* __restrict__ fc_b,
                        float* __restrict__ out, int G) {
  int g = blockIdx.x * blockDim.x + threadIdx.x;
  if (g < G) {
    float acc = 0.f;
    for (int d = 0; d < NODE_DIM; ++d) acc += pooled[g * NODE_DIM + d] * fc_w[d];
    float c = counts[g];
    if (c < 1.f) c = 1.f;
    out[g] = acc / c + fc_b[0];
  }
}

extern "C" void kernel_launch(void* const* d_in, const int* in_sizes, int n_in,
                              void* d_out, int out_size, void* d_ws, size_t ws_size,
                              hipStream_t stream) {
  const int*   atoms   = (const int*)  d_in[0];
  const int*   eidx    = (const int*)  d_in[1];
  const float* coords  = (const float*)d_in[2];
  const int*   isr     = (const int*)  d_in[3];
  const int*   batch   = (const int*)  d_in[4];
  const float* embed_w = (const float*)d_in[5];
  const float* sub_w   = (const float*)d_in[6];
  const float* W1      = (const float*)d_in[7];
  const float* b1      = (const float*)d_in[8];
  const float* W2      = (const float*)d_in[9];
  const float* b2      = (const float*)d_in[10];
  const float* fc_w    = (const float*)d_in[11];
  const float* fc_b    = (const float*)d_in[12];
  float* out = (float*)d_out;

  const int N = in_sizes[0];
  const int E = in_sizes[1] / 2;
  const int L = in_sizes[8] / HIDDEN;
  const int G = out_size;

  const int* srcv = eidx;
  const int* dstv = eidx + E;

  size_t off = 0;
  auto carve = [&](size_t bytes) -> char* {
    char* p = (char*)d_ws + off;
    off += (bytes + 255) & ~(size_t)255;
    return p;
  };
  float* hf     = (float*)carve((size_t)N * NODE_DIM * 4);
  short* hb     = (short*)carve((size_t)N * NODE_DIM * 2);
  float* S      = (float*)carve((size_t)N * HIDDEN * 4);
  short* pa     = (short*)carve((size_t)N * HIDDEN * 2);
  short* pb     = (short*)carve((size_t)N * HIDDEN * 2);
  float* distk  = (float*)carve((size_t)E * 4);
  int*   cnts   = (int*)  carve((size_t)N * 4);
  int*   cursor = (int*)  carve((size_t)N * 4);
  int2*  sd_p   = (int2*) carve((size_t)E * 8);
  int*   de_p   = (int*)  carve((size_t)E * 4);
  int*   part   = (int*)  carve(((size_t)N / 256 + 2) * 4);
  short* W1abp  = (short*)carve((size_t)L * L1ABSZ * 2);
  short* W1cp   = (short*)carve((size_t)L * L1CSZ * 2);
  short* W2p    = (short*)carve((size_t)L * L2SZ * 2);
  float* pooled = (float*)carve((size_t)G * NODE_DIM * 4);
  float* cntg   = (float*)carve((size_t)G * 4);

  const int nbN = (N + 255) / 256;

  k_init<<<1024, 256, 0, stream>>>(atoms, embed_w, hf, hb, N * NODE_DIM);
  k_zero4<<<2048, 256, 0, stream>>>((float4*)S, N * HIDDEN / 4);
  k_edge_pre<<<1024, 256, 0, stream>>>(srcv, dstv, coords, isr, distk, E);
  k_zero_i<<<nbN, 256, 0, stream>>>(cnts, N);
  k_zero_f<<<(G * NODE_DIM + G + 255) / 256, 256, 0, stream>>>(pooled, G * NODE_DIM + G);
  k_hist<<<1024, 256, 0, stream>>>(dstv, cnts, E);
  k_scan_part<<<nbN, 256, 0, stream>>>(cnts, part, N);
  k_scan_top<<<1, 512, 0, stream>>>(part, nbN);
  k_scan_apply<<<nbN, 256, 0, stream>>>(cnts, part, cursor, N);
  k_build<<<1024, 256, 0, stream>>>(srcv, dstv, distk, cursor, sd_p, de_p, E);
  k_pack_w1ab<<<(L * L1ABSZ + 255) / 256, 256, 0, stream>>>(W1, W1abp, L * L1ABSZ);
  k_pack_w1c<<<(L * L1CSZ + 255) / 256, 256, 0, stream>>>(W1, W1cp, L * L1CSZ);
  k_pack_w2<<<(L * L2SZ + 255) / 256, 256, 0, stream>>>(W2, W2p, L * L2SZ);

  const int nblk_n = (N + 63) / 64;
  const int nblk_e = (E + TE - 1) / TE;
  for (int l = 0; l < L; ++l) {
    k_node<<<nblk_n, 256, 0, stream>>>(
        hf, hb, S, cnts,
        (l > 0) ? W2p + (size_t)(l - 1) * L2SZ : (const short*)nullptr,
        (l > 0) ? b2 + (size_t)(l - 1) * NODE_DIM : (const float*)nullptr,
        W1abp + (size_t)l * L1ABSZ, b1 + (size_t)l * HIDDEN,
        pa, pb, N);
    k_edge<<<nblk_e, 256, 0, stream>>>(pa, pb, sd_p, de_p, sub_w,
                                       W1cp + (size_t)l * L1CSZ, S, E);
  }
  k_node<<<nblk_n, 256, 0, stream>>>(
      hf, hb, S, cnts,
      W2p + (size_t)(L - 1) * L2SZ, b2 + (size_t)(L - 1) * NODE_DIM,
      (const short*)nullptr, (const float*)nullptr, pa, pb, N);

  k_pool<<<(N + 63) / 64, 64, 0, stream>>>(hf, batch, pooled, cntg, N);
  k_final<<<1, 64, 0, stream>>>(pooled, cntg, fc_w, fc_b, out, G);
}

// Round 7
// 828.146 us; speedup vs baseline: 1.5113x; 1.0175x over previous
//
#include <hip/hip_runtime.h>
#include <hip/hip_bf16.h>
#include <math.h>

#define NODE_DIM  64
#define EDGE_DIM  32
#define NUM_GAUSS 16
#define HIDDEN    128
#define CAT_DIM   160
#define TE        128                   // edges per block in edge kernel
#define ES        136                   // eac LDS row stride (shorts)
#define L1ABSZ    (64 * 256)            // packed W1ab per layer (K=64, N=256)
#define L1CSZ     (32 * 128)            // packed W1c per layer  (K=32, N=128)
#define L2SZ      (HIDDEN * NODE_DIM)   // packed W2 per layer   (K=128, N=64)

typedef __attribute__((ext_vector_type(8))) short short8;
typedef __attribute__((ext_vector_type(4))) float float4v;

static __device__ __forceinline__ short f2bf(float x) {
  __hip_bfloat16 h = __float2bfloat16(x);
  return *reinterpret_cast<short*>(&h);
}
static __device__ __forceinline__ float bflo(unsigned u) { return __uint_as_float(u << 16); }
static __device__ __forceinline__ float bfhi(unsigned u) { return __uint_as_float(u & 0xffff0000u); }

// ---------------- init: h_f32 = embed[atoms], h_bf16 mirror ----------------
__global__ void k_init(const int* __restrict__ atoms, const float* __restrict__ embed_w,
                       float* __restrict__ hf, short* __restrict__ hb, int n) {
  int stride = gridDim.x * blockDim.x;
  for (int i = blockIdx.x * blockDim.x + threadIdx.x; i < n; i += stride) {
    float f = embed_w[atoms[i >> 6] * NODE_DIM + (i & 63)];
    hf[i] = f;
    hb[i] = f2bf(f);
  }
}

__global__ void k_zero_f(float* __restrict__ p, int n) {
  int stride = gridDim.x * blockDim.x;
  for (int i = blockIdx.x * blockDim.x + threadIdx.x; i < n; i += stride) p[i] = 0.f;
}
__global__ void k_zero_i(int* __restrict__ p, int n) {
  int i = blockIdx.x * blockDim.x + threadIdx.x;
  if (i < n) p[i] = 0;
}
__global__ void k_zero4(float4* __restrict__ p, int n4) {
  int stride = gridDim.x * blockDim.x;
  for (int i = blockIdx.x * blockDim.x + threadIdx.x; i < n4; i += stride)
    p[i] = make_float4(0.f, 0.f, 0.f, 0.f);
}

// ---------------- edge precompute: distk = (+/-)dist, sign encodes kind ----------------
__global__ void k_edge_pre(const int* __restrict__ src, const int* __restrict__ dst,
                           const float* __restrict__ coords, const int* __restrict__ isr,
                           float* __restrict__ distk, int E) {
  int stride = gridDim.x * blockDim.x;
  for (int e = blockIdx.x * blockDim.x + threadIdx.x; e < E; e += stride) {
    int s = src[e], d = dst[e];
    float dx = coords[s*3+0] - coords[d*3+0];
    float dy = coords[s*3+1] - coords[d*3+1];
    float dz = coords[s*3+2] - coords[d*3+2];
    float dist = sqrtf(dx*dx + dy*dy + dz*dz);
    distk[e] = (isr[s] != isr[d]) ? -dist : dist;
  }
}

// ---------------- CSR-order build ----------------
__global__ void k_hist(const int* __restrict__ dst, int* __restrict__ counts, int E) {
  int stride = gridDim.x * blockDim.x;
  for (int e = blockIdx.x * blockDim.x + threadIdx.x; e < E; e += stride)
    atomicAdd(&counts[dst[e]], 1);
}

// hierarchical exclusive scan: partials -> top scan -> apply
__global__ void k_scan_part(const int* __restrict__ counts, int* __restrict__ part, int N) {
  __shared__ int red[256];
  int t = threadIdx.x;
  int i = blockIdx.x * 256 + t;
  red[t] = (i < N) ? counts[i] : 0;
  __syncthreads();
  for (int o = 128; o > 0; o >>= 1) {
    if (t < o) red[t] += red[t + o];
    __syncthreads();
  }
  if (t == 0) part[blockIdx.x] = red[0];
}

__global__ void k_scan_top(int* __restrict__ part, int nb) {
  __shared__ int s[512];
  int t = threadIdx.x;
  int v = (t < nb) ? part[t] : 0;
  s[t] = v;
  __syncthreads();
  for (int o = 1; o < 512; o <<= 1) {
    int u = (t >= o) ? s[t - o] : 0;
    __syncthreads();
    s[t] += u;
    __syncthreads();
  }
  if (t < nb) part[t] = s[t] - v;   // exclusive
}

__global__ void k_scan_apply(const int* __restrict__ counts, const int* __restrict__ part,
                             int* __restrict__ cursor, int* __restrict__ colptr, int N) {
  __shared__ int s[256];
  int t = threadIdx.x;
  int i = blockIdx.x * 256 + t;
  int v = (i < N) ? counts[i] : 0;
  s[t] = v;
  __syncthreads();
  for (int o = 1; o < 256; o <<= 1) {
    int u = (t >= o) ? s[t - o] : 0;
    __syncthreads();
    s[t] += u;
    __syncthreads();
  }
  if (i < N) {
    int ex = part[blockIdx.x] + s[t] - v;   // exclusive prefix
    cursor[i] = ex;
    colptr[i] = ex;
  }
}

// mark nodes whose dst-sorted segment crosses a TE block boundary
__global__ void k_mark(const int* __restrict__ colptr, int* __restrict__ bn,
                       int* __restrict__ bn_cnt, int N, int E) {
  int i = blockIdx.x * 256 + threadIdx.x;
  if (i >= N) return;
  int s = colptr[i];
  int e = (i == N - 1) ? E : colptr[i + 1];
  if (e > s && (s / TE) != ((e - 1) / TE)) {
    int p = atomicAdd(bn_cnt, 1);
    bn[p] = i;
  }
}

// zero S rows of boundary nodes (wave per row)
__global__ void k_zrows(float* __restrict__ S, const int* __restrict__ bn,
                        const int* __restrict__ bn_cnt) {
  int cnt = bn_cnt[0];
  int lane = threadIdx.x & 63;
  int wpb  = blockDim.x >> 6;
  int stride = gridDim.x * wpb;
  for (int idx = blockIdx.x * wpb + (threadIdx.x >> 6); idx < cnt; idx += stride) {
    int row = bn[idx];
    *(float2*)&S[(size_t)row * 128 + lane * 2] = make_float2(0.f, 0.f);
  }
}

// scatter edges into dst-sorted order: (src, dist) as int2, de separate
__global__ void k_build(const int* __restrict__ src, const int* __restrict__ dst,
                        const float* __restrict__ distk, int* __restrict__ cursor,
                        int2* __restrict__ sd_p, int* __restrict__ de_p, int E) {
  int stride = gridDim.x * blockDim.x;
  for (int e = blockIdx.x * blockDim.x + threadIdx.x; e < E; e += stride) {
    int d = dst[e];
    int p = atomicAdd(&cursor[d], 1);
    sd_p[p] = make_int2(src[e], __float_as_int(distk[e]));
    de_p[p] = d;
  }
}

// ---------------- weight packing (B-fragment order: ((kt*4+quad)*N + n)*8 + j) ----------------
__global__ void k_pack_w1ab(const float* __restrict__ W1, short* __restrict__ Wp, int total) {
  int i = blockIdx.x * blockDim.x + threadIdx.x;
  if (i >= total) return;
  int l = i / L1ABSZ, r = i % L1ABSZ;
  int k = r / 256, n = r % 256;
  int kt = k >> 5, quad = (k >> 3) & 3, j = k & 7;
  int srow = (n < 128) ? k : 64 + k;
  int scol = (n < 128) ? n : n - 128;
  Wp[l * L1ABSZ + ((kt*4 + quad) * 256 + n) * 8 + j] =
      f2bf(W1[(size_t)l * CAT_DIM * HIDDEN + srow * HIDDEN + scol]);
}
__global__ void k_pack_w1c(const float* __restrict__ W1, short* __restrict__ Wp, int total) {
  int i = blockIdx.x * blockDim.x + threadIdx.x;
  if (i >= total) return;
  int l = i / L1CSZ, r = i % L1CSZ;
  int k = r / 128, n = r % 128;
  int quad = k >> 3, j = k & 7;
  Wp[l * L1CSZ + (quad * 128 + n) * 8 + j] =
      f2bf(W1[(size_t)l * CAT_DIM * HIDDEN + (128 + k) * HIDDEN + n]);
}
__global__ void k_pack_w2(const float* __restrict__ W, short* __restrict__ Wp, int total) {
  int i = blockIdx.x * blockDim.x + threadIdx.x;
  if (i >= total) return;
  int l = i / L2SZ, r = i % L2SZ;
  int k = r / NODE_DIM, n = r % NODE_DIM;
  int kt = k >> 5, quad = (k >> 3) & 3, j = k & 7;
  Wp[l * L2SZ + ((kt*4 + quad) * NODE_DIM + n) * 8 + j] = f2bf(W[i]);
}

// ---------------- node kernel: [agg=S@W2+cnt*b2; h=relu(h+agg)] ; [pa|pb = h@W1ab] ----------------
__global__ __launch_bounds__(256, 3) void k_node(
    float* __restrict__ hf, const short* __restrict__ hb,
    const float* __restrict__ S, const int* __restrict__ cnts,
    const short* __restrict__ W2p, const float* __restrict__ b2,
    const short* __restrict__ W1abp, const float* __restrict__ b1,
    short* __restrict__ pa, short* __restrict__ pb, int N)
{
  __shared__ short ht[64 * 72];

  const int tid  = threadIdx.x;
  const int lane = tid & 63;
  const int w    = tid >> 6;
  const int quad = lane >> 4;
  const int l16  = lane & 15;
  const int base = blockIdx.x * 64 + w * 16;

  if (W2p) {
    float4v acc[4];
    #pragma unroll
    for (int nt = 0; nt < 4; ++nt) acc[nt] = (float4v)0.f;
    const int arow = base + l16;
    const bool av = arow < N;
    #pragma unroll
    for (int kt = 0; kt < 4; ++kt) {
      short8 a;
      if (av) {
        const float* sp = &S[(size_t)arow * 128 + kt*32 + quad*8];
        float4 x0 = *(const float4*)sp;
        float4 x1 = *(const float4*)(sp + 4);
        a[0]=f2bf(x0.x); a[1]=f2bf(x0.y); a[2]=f2bf(x0.z); a[3]=f2bf(x0.w);
        a[4]=f2bf(x1.x); a[5]=f2bf(x1.y); a[6]=f2bf(x1.z); a[7]=f2bf(x1.w);
      } else a = (short8)0;
      #pragma unroll
      for (int nt = 0; nt < 4; ++nt) {
        short8 b = *(const short8*)&W2p[((kt*4 + quad) * NODE_DIM + nt*16 + l16) * 8];
        acc[nt] = __builtin_amdgcn_mfma_f32_16x16x32_bf16(a, b, acc[nt], 0, 0, 0);
      }
    }
    float cf[4];
    #pragma unroll
    for (int r = 0; r < 4; ++r) {
      int row = base + quad*4 + r;
      cf[r] = (row < N) ? (float)cnts[row] : 0.f;
    }
    #pragma unroll
    for (int nt = 0; nt < 4; ++nt) {
      int col = nt*16 + l16;
      float bb = b2[col];
      #pragma unroll
      for (int r = 0; r < 4; ++r) {
        int row = base + quad*4 + r;
        int lrow = w*16 + quad*4 + r;
        if (row < N) {
          float v = hf[(size_t)row * 64 + col] + acc[nt][r] + cf[r] * bb;
          v = fmaxf(v, 0.f);
          hf[(size_t)row * 64 + col] = v;
          ht[lrow * 72 + col] = f2bf(v);
        } else {
          ht[lrow * 72 + col] = 0;
        }
      }
    }
  } else {
    int row = base + l16;
    #pragma unroll
    for (int c = 0; c < 2; ++c) {
      int colc = quad*16 + c*8;
      short8 v = (row < N) ? *(const short8*)&hb[(size_t)row * 64 + colc] : (short8)0;
      *(short8*)&ht[(w*16 + l16) * 72 + colc] = v;
    }
  }

  if (W1abp) {
    float4v acc[16];
    #pragma unroll
    for (int nt = 0; nt < 16; ++nt) acc[nt] = (float4v)0.f;
    #pragma unroll
    for (int kt = 0; kt < 2; ++kt) {
      short8 a = *(const short8*)&ht[(w*16 + l16) * 72 + kt*32 + quad*8];
      #pragma unroll
      for (int nt = 0; nt < 16; ++nt) {
        short8 b = *(const short8*)&W1abp[((kt*4 + quad) * 256 + nt*16 + l16) * 8];
        acc[nt] = __builtin_amdgcn_mfma_f32_16x16x32_bf16(a, b, acc[nt], 0, 0, 0);
      }
    }
    #pragma unroll
    for (int nt = 0; nt < 16; ++nt) {
      int col = nt*16 + l16;
      float bb = (col < 128) ? b1[col] : 0.f;
      #pragma unroll
      for (int r = 0; r < 4; ++r) {
        int row = base + quad*4 + r;
        if (row < N) {
          float v = acc[nt][r] + bb;
          if (col < 128) pa[(size_t)row * 128 + col]         = f2bf(v);
          else           pb[(size_t)row * 128 + (col - 128)] = f2bf(v);
        }
      }
    }
  }
}

// ---------------- edge kernel: eac MFMA + pipelined gather/silu/segmented-sum ----------------
__global__ __launch_bounds__(256, 4) void k_edge(
    const short* __restrict__ pa, const short* __restrict__ pb,
    const int2* __restrict__ sd_p, const int* __restrict__ de_p,
    const float* __restrict__ sub_w,
    const short* __restrict__ W1cp,
    float* __restrict__ S, int E)
{
  __shared__ short eac[TE * ES];
  __shared__ __align__(16) int ses[TE], des[TE];
  __shared__ float dks[TE];

  const int tid  = threadIdx.x;
  const int lane = tid & 63;
  const int w    = tid >> 6;
  const int quad = lane >> 4;
  const int l16  = lane & 15;
  const int ebase = blockIdx.x * TE;

  if (tid < TE) {
    int ge = ebase + tid;
    if (ge < E) {
      int2 v = sd_p[ge];
      ses[tid] = v.x;
      dks[tid] = __int_as_float(v.y);
      des[tid] = de_p[ge];
    } else {
      ses[tid] = 0; des[tid] = -1; dks[tid] = 0.f;
    }
  }
  __syncthreads();

  // ---- phase 1: eac = ea @ W1c for rows [w*32, w*32+32) ----
  {
    const int c0 = quad * 8;
    short8 ea[2];
    #pragma unroll
    for (int mt = 0; mt < 2; ++mt) {
      float dk = dks[w*32 + mt*16 + l16];
      if (quad < 2) {
        float dist = fabsf(dk);
        #pragma unroll
        for (int j = 0; j < 8; ++j) {
          float t = dist - (float)(c0 + j) * (1.0f / 3.0f);
          ea[mt][j] = f2bf(__expf(-4.5f * t * t));
        }
      } else {
        int kk = (int)(__float_as_uint(dk) >> 31);
        const float* sw = &sub_w[kk * NUM_GAUSS + (c0 - 16)];
        #pragma unroll
        for (int j = 0; j < 8; ++j) ea[mt][j] = f2bf(sw[j]);
      }
    }
    float4v acc[2][8];
    #pragma unroll
    for (int mt = 0; mt < 2; ++mt)
      #pragma unroll
      for (int nt = 0; nt < 8; ++nt) acc[mt][nt] = (float4v)0.f;
    #pragma unroll
    for (int nt = 0; nt < 8; ++nt) {
      short8 b = *(const short8*)&W1cp[(quad * 128 + nt*16 + l16) * 8];
      acc[0][nt] = __builtin_amdgcn_mfma_f32_16x16x32_bf16(ea[0], b, acc[0][nt], 0, 0, 0);
      acc[1][nt] = __builtin_amdgcn_mfma_f32_16x16x32_bf16(ea[1], b, acc[1][nt], 0, 0, 0);
    }
    #pragma unroll
    for (int mt = 0; mt < 2; ++mt)
      #pragma unroll
      for (int nt = 0; nt < 8; ++nt)
        #pragma unroll
        for (int r = 0; r < 4; ++r)
          eac[(w*32 + mt*16 + quad*4 + r) * ES + nt*16 + l16] = f2bf(acc[mt][nt][r]);
  }
  // wave-private rows: same wave consumes below; in-order LDS, no barrier

  // ---- phase 2: 2-deep pipelined gathers + silu + run-length segmented sum ----
  {
    const int d2 = lane * 2;
    int prev_d = (w > 0) ? des[w*32 - 1] : ((ebase > 0) ? de_p[ebase - 1] : -1);
    int next_d = (w < 3) ? des[w*32 + 32] : ((ebase + TE < E) ? de_p[ebase + TE] : -1);

    unsigned ub[2][8], ue[2][8], pz[2][8];
    int      dd[2][8];

    auto loadg = [&](int buf, int g) {
      const int rowb = w*32 + g*8;
      int4 dA = *(const int4*)&des[rowb];
      int4 dB = *(const int4*)&des[rowb + 4];
      int4 sA = *(const int4*)&ses[rowb];
      int4 sB = *(const int4*)&ses[rowb + 4];
      int dv[8] = {dA.x, dA.y, dA.z, dA.w, dB.x, dB.y, dB.z, dB.w};
      int sv[8] = {sA.x, sA.y, sA.z, sA.w, sB.x, sB.y, sB.z, sB.w};
      #pragma unroll
      for (int j = 0; j < 8; ++j) {
        int sn = __builtin_amdgcn_readfirstlane(sv[j]);
        int dn = __builtin_amdgcn_readfirstlane(dv[j]);
        dd[buf][j] = dn;
        ub[buf][j] = *(const unsigned*)&pb[(size_t)sn * 128 + d2];
        pz[buf][j] = (dn >= 0) ? *(const unsigned*)&pa[(size_t)dn * 128 + d2] : 0u;
        ue[buf][j] = *(const unsigned*)&eac[(rowb + j) * ES + d2];
      }
    };

    int   cur = -2;
    float s0 = 0.f, s1 = 0.f;
    float p0 = 0.f, p1 = 0.f;
    bool  openL = false;

    auto consume = [&](int buf, int g) {
      #pragma unroll
      for (int j = 0; j < 8; ++j) {
        int d = dd[buf][j];
        if (d != cur) {
          if (cur >= 0) {
            if (openL) {
              atomicAdd(&S[(size_t)cur * 128 + d2],     s0);
              atomicAdd(&S[(size_t)cur * 128 + d2 + 1], s1);
            } else {
              *(float2*)&S[(size_t)cur * 128 + d2] = make_float2(s0, s1);
            }
          }
          cur = d; s0 = 0.f; s1 = 0.f;
          openL = (g == 0) && (j == 0) && (prev_d == d);
          p0 = bflo(pz[buf][j]); p1 = bfhi(pz[buf][j]);
        }
        if (cur >= 0) {
          float x0 = p0 + bflo(ub[buf][j]) + bflo(ue[buf][j]);
          float x1 = p1 + bfhi(ub[buf][j]) + bfhi(ue[buf][j]);
          s0 += x0 * __builtin_amdgcn_rcpf(1.f + __expf(-x0));
          s1 += x1 * __builtin_amdgcn_rcpf(1.f + __expf(-x1));
        }
      }
    };

    loadg(0, 0);
    loadg(1, 1);
    consume(0, 0);
    loadg(0, 2);
    consume(1, 1);
    loadg(1, 3);
    consume(0, 2);
    consume(1, 3);

    if (cur >= 0) {
      bool openR = (next_d == cur);
      if (openL || openR) {
        atomicAdd(&S[(size_t)cur * 128 + d2],     s0);
        atomicAdd(&S[(size_t)cur * 128 + d2 + 1], s1);
      } else {
        *(float2*)&S[(size_t)cur * 128 + d2] = make_float2(s0, s1);
      }
    }
  }
}

// ---------------- mean pool (batch_ids sorted): wave per 64 nodes ----------------
__global__ void k_pool(const float* __restrict__ h, const int* __restrict__ batch_ids,
                       float* __restrict__ pooled, float* __restrict__ counts, int N) {
  int lane = threadIdx.x & 63;
  int base = blockIdx.x * 64;
  float acc = 0.f;
  int   cnt = 0;
  int  gcur = -1;
  for (int n = 0; n < 64; ++n) {
    int node = base + n;
    if (node >= N) break;
    int g = batch_ids[node];
    if (g != gcur) {
      if (gcur >= 0) {
        atomicAdd(&pooled[gcur * NODE_DIM + lane], acc);
        if (lane == 0) atomicAdd(&counts[gcur], (float)cnt);
      }
      gcur = g; acc = 0.f; cnt = 0;
    }
    acc += h[(size_t)node * NODE_DIM + lane];
    cnt++;
  }
  if (gcur >= 0) {
    atomicAdd(&pooled[gcur * NODE_DIM + lane], acc);
    if (lane == 0) atomicAdd(&counts[gcur], (float)cnt);
  }
}

__global__ void k_final(const float* __restrict__ pooled, const float* __restrict__ counts,
                        const float* __restrict__ fc_w, const float* __restrict__ fc_b,
                        float* __restrict__ out, int G) {
  int g = blockIdx.x * blockDim.x + threadIdx.x;
  if (g < G) {
    float acc = 0.f;
    for (int d = 0; d < NODE_DIM; ++d) acc += pooled[g * NODE_DIM + d] * fc_w[d];
    float c = counts[g];
    if (c < 1.f) c = 1.f;
    out[g] = acc / c + fc_b[0];
  }
}

extern "C" void kernel_launch(void* const* d_in, const int* in_sizes, int n_in,
                              void* d_out, int out_size, void* d_ws, size_t ws_size,
                              hipStream_t stream) {
  const int*   atoms   = (const int*)  d_in[0];
  const int*   eidx    = (const int*)  d_in[1];
  const float* coords  = (const float*)d_in[2];
  const int*   isr     = (const int*)  d_in[3];
  const int*   batch   = (const int*)  d_in[4];
  const float* embed_w = (const float*)d_in[5];
  const float* sub_w   = (const float*)d_in[6];
  const float* W1      = (const float*)d_in[7];
  const float* b1      = (const float*)d_in[8];
  const float* W2      = (const float*)d_in[9];
  const float* b2      = (const float*)d_in[10];
  const float* fc_w    = (const float*)d_in[11];
  const float* fc_b    = (const float*)d_in[12];
  float* out = (float*)d_out;

  const int N = in_sizes[0];
  const int E = in_sizes[1] / 2;
  const int L = in_sizes[8] / HIDDEN;
  const int G = out_size;

  const int* srcv = eidx;
  const int* dstv = eidx + E;

  size_t off = 0;
  auto carve = [&](size_t bytes) -> char* {
    char* p = (char*)d_ws + off;
    off += (bytes + 255) & ~(size_t)255;
    return p;
  };
  float* hf     = (float*)carve((size_t)N * NODE_DIM * 4);
  short* hb     = (short*)carve((size_t)N * NODE_DIM * 2);
  float* S      = (float*)carve((size_t)N * HIDDEN * 4);
  short* pa     = (short*)carve((size_t)N * HIDDEN * 2);
  short* pb     = (short*)carve((size_t)N * HIDDEN * 2);
  float* distk  = (float*)carve((size_t)E * 4);
  int*   cnts   = (int*)  carve((size_t)N * 4);
  int*   cursor = (int*)  carve((size_t)N * 4);
  int*   colptr = (int*)  carve((size_t)N * 4);
  int*   bn     = (int*)  carve((size_t)N * 4);
  int*   bn_cnt = (int*)  carve(256);
  int2*  sd_p   = (int2*) carve((size_t)E * 8);
  int*   de_p   = (int*)  carve((size_t)E * 4);
  int*   part   = (int*)  carve(((size_t)N / 256 + 2) * 4);
  short* W1abp  = (short*)carve((size_t)L * L1ABSZ * 2);
  short* W1cp   = (short*)carve((size_t)L * L1CSZ * 2);
  short* W2p    = (short*)carve((size_t)L * L2SZ * 2);
  float* pooled = (float*)carve((size_t)G * NODE_DIM * 4);
  float* cntg   = (float*)carve((size_t)G * 4);

  const int nbN = (N + 255) / 256;

  k_init<<<1024, 256, 0, stream>>>(atoms, embed_w, hf, hb, N * NODE_DIM);
  k_zero4<<<2048, 256, 0, stream>>>((float4*)S, N * HIDDEN / 4);
  k_edge_pre<<<1024, 256, 0, stream>>>(srcv, dstv, coords, isr, distk, E);
  k_zero_i<<<nbN, 256, 0, stream>>>(cnts, N);
  k_zero_i<<<1, 256, 0, stream>>>(bn_cnt, 1);
  k_zero_f<<<(G * NODE_DIM + G + 255) / 256, 256, 0, stream>>>(pooled, G * NODE_DIM + G);
  k_hist<<<1024, 256, 0, stream>>>(dstv, cnts, E);
  k_scan_part<<<nbN, 256, 0, stream>>>(cnts, part, N);
  k_scan_top<<<1, 512, 0, stream>>>(part, nbN);
  k_scan_apply<<<nbN, 256, 0, stream>>>(cnts, part, cursor, colptr, N);
  k_mark<<<nbN, 256, 0, stream>>>(colptr, bn, bn_cnt, N, E);
  k_build<<<1024, 256, 0, stream>>>(srcv, dstv, distk, cursor, sd_p, de_p, E);
  k_pack_w1ab<<<(L * L1ABSZ + 255) / 256, 256, 0, stream>>>(W1, W1abp, L * L1ABSZ);
  k_pack_w1c<<<(L * L1CSZ + 255) / 256, 256, 0, stream>>>(W1, W1cp, L * L1CSZ);
  k_pack_w2<<<(L * L2SZ + 255) / 256, 256, 0, stream>>>(W2, W2p, L * L2SZ);

  const int nblk_n = (N + 63) / 64;
  const int nblk_e = (E + TE - 1) / TE;
  for (int l = 0; l < L; ++l) {
    k_node<<<nblk_n, 256, 0, stream>>>(
        hf, hb, S, cnts,
        (l > 0) ? W2p + (size_t)(l - 1) * L2SZ : (const short*)nullptr,
        (l > 0) ? b2 + (size_t)(l - 1) * NODE_DIM : (const float*)nullptr,
        W1abp + (size_t)l * L1ABSZ, b1 + (size_t)l * HIDDEN,
        pa, pb, N);
    if (l > 0)
      k_zrows<<<128, 256, 0, stream>>>(S, bn, bn_cnt);
    k_edge<<<nblk_e, 256, 0, stream>>>(pa, pb, sd_p, de_p, sub_w,
                                       W1cp + (size_t)l * L1CSZ, S, E);
  }
  k_node<<<nblk_n, 256, 0, stream>>>(
      hf, hb, S, cnts,
      W2p + (size_t)(L - 1) * L2SZ, b2 + (size_t)(L - 1) * NODE_DIM,
      (const short*)nullptr, (const float*)nullptr, pa, pb, N);

  k_pool<<<(N + 63) / 64, 64, 0, stream>>>(hf, batch, pooled, cntg, N);
  k_final<<<1, 64, 0, stream>>>(pooled, cntg, fc_w, fc_b, out, G);
}

// Round 8
// 815.833 us; speedup vs baseline: 1.5341x; 1.0151x over previous
//
#include <hip/hip_runtime.h>
#include <hip/hip_bf16.h>
#include <math.h>

#define NODE_DIM  64
#define EDGE_DIM  32
#define NUM_GAUSS 16
#define HIDDEN    128
#define CAT_DIM   160
#define TE        128                   // edges per block in edge kernel
#define TBL_BINS  2048
#define TBL_SCALE 256.0f                // bins per unit distance (domain [0,8))
#define L1ABSZ    (64 * 256)            // packed W1ab per layer (K=64, N=256)
#define L2SZ      (HIDDEN * NODE_DIM)   // packed W2 per layer   (K=128, N=64)
#define TBLSZ     (2 * TBL_BINS * 128)  // per-layer edge-attr table entries

typedef __attribute__((ext_vector_type(8))) short short8;
typedef __attribute__((ext_vector_type(4))) float float4v;

static __device__ __forceinline__ short f2bf(float x) {
  __hip_bfloat16 h = __float2bfloat16(x);
  return *reinterpret_cast<short*>(&h);
}
static __device__ __forceinline__ float bflo(unsigned u) { return __uint_as_float(u << 16); }
static __device__ __forceinline__ float bfhi(unsigned u) { return __uint_as_float(u & 0xffff0000u); }

// ---------------- init: h_f32 = embed[atoms], h_bf16 mirror ----------------
__global__ void k_init(const int* __restrict__ atoms, const float* __restrict__ embed_w,
                       float* __restrict__ hf, short* __restrict__ hb, int n) {
  int stride = gridDim.x * blockDim.x;
  for (int i = blockIdx.x * blockDim.x + threadIdx.x; i < n; i += stride) {
    float f = embed_w[atoms[i >> 6] * NODE_DIM + (i & 63)];
    hf[i] = f;
    hb[i] = f2bf(f);
  }
}

__global__ void k_zero_f(float* __restrict__ p, int n) {
  int stride = gridDim.x * blockDim.x;
  for (int i = blockIdx.x * blockDim.x + threadIdx.x; i < n; i += stride) p[i] = 0.f;
}
__global__ void k_zero_i(int* __restrict__ p, int n) {
  int i = blockIdx.x * blockDim.x + threadIdx.x;
  if (i < n) p[i] = 0;
}
__global__ void k_zero4(float4* __restrict__ p, int n4) {
  int stride = gridDim.x * blockDim.x;
  for (int i = blockIdx.x * blockDim.x + threadIdx.x; i < n4; i += stride)
    p[i] = make_float4(0.f, 0.f, 0.f, 0.f);
}

// ---------------- edge precompute: ety = (kind<<11) | bin(dist) ----------------
__global__ void k_edge_pre(const int* __restrict__ src, const int* __restrict__ dst,
                           const float* __restrict__ coords, const int* __restrict__ isr,
                           int* __restrict__ ety, int E) {
  int stride = gridDim.x * blockDim.x;
  for (int e = blockIdx.x * blockDim.x + threadIdx.x; e < E; e += stride) {
    int s = src[e], d = dst[e];
    float dx = coords[s*3+0] - coords[d*3+0];
    float dy = coords[s*3+1] - coords[d*3+1];
    float dz = coords[s*3+2] - coords[d*3+2];
    float dist = sqrtf(dx*dx + dy*dy + dz*dz);
    int bin = (int)(dist * TBL_SCALE);
    bin = (bin > TBL_BINS - 1) ? TBL_BINS - 1 : bin;
    int kind = (isr[s] != isr[d]) ? 1 : 0;
    ety[e] = (kind << 11) | bin;
  }
}

// ---------------- edge-attr table: tbl[l][kind][bin][col] = rbf(bin)@W1c + sub_w[kind]@W1c ----------------
__global__ void k_tbl(const float* __restrict__ W1, const float* __restrict__ sub_w,
                      short* __restrict__ tbl, int total) {
  int idx = blockIdx.x * 256 + threadIdx.x;   // thread per (l, kind, bin)
  if (idx >= total) return;
  int bin  = idx & (TBL_BINS - 1);
  int kind = (idx >> 11) & 1;
  int l    = idx >> 12;
  float dist = ((float)bin + 0.5f) * (1.0f / TBL_SCALE);
  float rbf[16], skv[16];
  #pragma unroll
  for (int g = 0; g < 16; ++g) {
    float t = dist - (float)g * (1.0f / 3.0f);
    rbf[g] = __expf(-4.5f * t * t);
    skv[g] = sub_w[kind * 16 + g];
  }
  const float* W1c = W1 + (size_t)l * CAT_DIM * HIDDEN + 128 * HIDDEN;
  short* outp = tbl + ((size_t)idx) * 128;
  #pragma unroll 4
  for (int col = 0; col < 128; ++col) {
    float acc = 0.f;
    #pragma unroll
    for (int g = 0; g < 16; ++g) acc += rbf[g] * W1c[g * 128 + col];
    #pragma unroll
    for (int g = 0; g < 16; ++g) acc += skv[g] * W1c[(16 + g) * 128 + col];
    outp[col] = f2bf(acc);
  }
}

// ---------------- CSR-order build ----------------
__global__ void k_hist(const int* __restrict__ dst, int* __restrict__ counts, int E) {
  int stride = gridDim.x * blockDim.x;
  for (int e = blockIdx.x * blockDim.x + threadIdx.x; e < E; e += stride)
    atomicAdd(&counts[dst[e]], 1);
}

// hierarchical exclusive scan: partials -> top scan -> apply (+ boundary-node marking)
__global__ void k_scan_part(const int* __restrict__ counts, int* __restrict__ part, int N) {
  __shared__ int red[256];
  int t = threadIdx.x;
  int i = blockIdx.x * 256 + t;
  red[t] = (i < N) ? counts[i] : 0;
  __syncthreads();
  for (int o = 128; o > 0; o >>= 1) {
    if (t < o) red[t] += red[t + o];
    __syncthreads();
  }
  if (t == 0) part[blockIdx.x] = red[0];
}

__global__ void k_scan_top(int* __restrict__ part, int nb, int* __restrict__ bn_cnt) {
  __shared__ int s[512];
  int t = threadIdx.x;
  if (t == 0) bn_cnt[0] = 0;
  int v = (t < nb) ? part[t] : 0;
  s[t] = v;
  __syncthreads();
  for (int o = 1; o < 512; o <<= 1) {
    int u = (t >= o) ? s[t - o] : 0;
    __syncthreads();
    s[t] += u;
    __syncthreads();
  }
  if (t < nb) part[t] = s[t] - v;   // exclusive
}

// apply: cursor = exclusive prefix; mark nodes whose segment crosses a 32-edge boundary
// (those rows receive atomicAdds in k_edge and must be pre-zeroed each layer)
__global__ void k_scan_apply(const int* __restrict__ counts, const int* __restrict__ part,
                             int* __restrict__ cursor,
                             int* __restrict__ bn, int* __restrict__ bn_cnt, int N) {
  __shared__ int s[256];
  int t = threadIdx.x;
  int i = blockIdx.x * 256 + t;
  int v = (i < N) ? counts[i] : 0;
  s[t] = v;
  __syncthreads();
  for (int o = 1; o < 256; o <<= 1) {
    int u = (t >= o) ? s[t - o] : 0;
    __syncthreads();
    s[t] += u;
    __syncthreads();
  }
  if (i < N) {
    int ex = part[blockIdx.x] + s[t] - v;   // exclusive prefix
    cursor[i] = ex;
    if (v > 0 && ((ex >> 5) != ((ex + v - 1) >> 5))) {
      int p = atomicAdd(bn_cnt, 1);
      bn[p] = i;
    }
  }
}

// zero S rows of boundary nodes (wave per row)
__global__ void k_zrows(float* __restrict__ S, const int* __restrict__ bn,
                        const int* __restrict__ bn_cnt) {
  int cnt = bn_cnt[0];
  int lane = threadIdx.x & 63;
  int wpb  = blockDim.x >> 6;
  int stride = gridDim.x * wpb;
  for (int idx = blockIdx.x * wpb + (threadIdx.x >> 6); idx < cnt; idx += stride) {
    int row = bn[idx];
    *(float2*)&S[(size_t)row * 128 + lane * 2] = make_float2(0.f, 0.f);
  }
}

// scatter edges into dst-sorted order: (src, ety) as int2, de separate
__global__ void k_build(const int* __restrict__ src, const int* __restrict__ dst,
                        const int* __restrict__ ety, int* __restrict__ cursor,
                        int2* __restrict__ sd_p, int* __restrict__ de_p, int E) {
  int stride = gridDim.x * blockDim.x;
  for (int e = blockIdx.x * blockDim.x + threadIdx.x; e < E; e += stride) {
    int d = dst[e];
    int p = atomicAdd(&cursor[d], 1);
    sd_p[p] = make_int2(src[e], ety[e]);
    de_p[p] = d;
  }
}

// ---------------- weight packing (B-fragment order: ((kt*4+quad)*N + n)*8 + j) ----------------
__global__ void k_pack_w1ab(const float* __restrict__ W1, short* __restrict__ Wp, int total) {
  int i = blockIdx.x * blockDim.x + threadIdx.x;
  if (i >= total) return;
  int l = i / L1ABSZ, r = i % L1ABSZ;
  int k = r / 256, n = r % 256;
  int kt = k >> 5, quad = (k >> 3) & 3, j = k & 7;
  int srow = (n < 128) ? k : 64 + k;
  int scol = (n < 128) ? n : n - 128;
  Wp[l * L1ABSZ + ((kt*4 + quad) * 256 + n) * 8 + j] =
      f2bf(W1[(size_t)l * CAT_DIM * HIDDEN + srow * HIDDEN + scol]);
}
__global__ void k_pack_w2(const float* __restrict__ W, short* __restrict__ Wp, int total) {
  int i = blockIdx.x * blockDim.x + threadIdx.x;
  if (i >= total) return;
  int l = i / L2SZ, r = i % L2SZ;
  int k = r / NODE_DIM, n = r % NODE_DIM;
  int kt = k >> 5, quad = (k >> 3) & 3, j = k & 7;
  Wp[l * L2SZ + ((kt*4 + quad) * NODE_DIM + n) * 8 + j] = f2bf(W[i]);
}

// ---------------- node kernel: [agg=S@W2+cnt*b2; h=relu(h+agg)] ; [pa|pb = h@W1ab] ----------------
__global__ __launch_bounds__(256, 3) void k_node(
    float* __restrict__ hf, const short* __restrict__ hb,
    const float* __restrict__ S, const int* __restrict__ cnts,
    const short* __restrict__ W2p, const float* __restrict__ b2,
    const short* __restrict__ W1abp, const float* __restrict__ b1,
    short* __restrict__ pa, short* __restrict__ pb, int N)
{
  __shared__ short ht[64 * 72];

  const int tid  = threadIdx.x;
  const int lane = tid & 63;
  const int w    = tid >> 6;
  const int quad = lane >> 4;
  const int l16  = lane & 15;
  const int base = blockIdx.x * 64 + w * 16;

  if (W2p) {
    float4v acc[4];
    #pragma unroll
    for (int nt = 0; nt < 4; ++nt) acc[nt] = (float4v)0.f;
    const int arow = base + l16;
    const bool av = arow < N;
    #pragma unroll
    for (int kt = 0; kt < 4; ++kt) {
      short8 a;
      if (av) {
        const float* sp = &S[(size_t)arow * 128 + kt*32 + quad*8];
        float4 x0 = *(const float4*)sp;
        float4 x1 = *(const float4*)(sp + 4);
        a[0]=f2bf(x0.x); a[1]=f2bf(x0.y); a[2]=f2bf(x0.z); a[3]=f2bf(x0.w);
        a[4]=f2bf(x1.x); a[5]=f2bf(x1.y); a[6]=f2bf(x1.z); a[7]=f2bf(x1.w);
      } else a = (short8)0;
      #pragma unroll
      for (int nt = 0; nt < 4; ++nt) {
        short8 b = *(const short8*)&W2p[((kt*4 + quad) * NODE_DIM + nt*16 + l16) * 8];
        acc[nt] = __builtin_amdgcn_mfma_f32_16x16x32_bf16(a, b, acc[nt], 0, 0, 0);
      }
    }
    float cf[4];
    #pragma unroll
    for (int r = 0; r < 4; ++r) {
      int row = base + quad*4 + r;
      cf[r] = (row < N) ? (float)cnts[row] : 0.f;
    }
    #pragma unroll
    for (int nt = 0; nt < 4; ++nt) {
      int col = nt*16 + l16;
      float bb = b2[col];
      #pragma unroll
      for (int r = 0; r < 4; ++r) {
        int row = base + quad*4 + r;
        int lrow = w*16 + quad*4 + r;
        if (row < N) {
          float v = hf[(size_t)row * 64 + col] + acc[nt][r] + cf[r] * bb;
          v = fmaxf(v, 0.f);
          hf[(size_t)row * 64 + col] = v;
          ht[lrow * 72 + col] = f2bf(v);
        } else {
          ht[lrow * 72 + col] = 0;
        }
      }
    }
  } else {
    int row = base + l16;
    #pragma unroll
    for (int c = 0; c < 2; ++c) {
      int colc = quad*16 + c*8;
      short8 v = (row < N) ? *(const short8*)&hb[(size_t)row * 64 + colc] : (short8)0;
      *(short8*)&ht[(w*16 + l16) * 72 + colc] = v;
    }
  }

  if (W1abp) {
    float4v acc[16];
    #pragma unroll
    for (int nt = 0; nt < 16; ++nt) acc[nt] = (float4v)0.f;
    #pragma unroll
    for (int kt = 0; kt < 2; ++kt) {
      short8 a = *(const short8*)&ht[(w*16 + l16) * 72 + kt*32 + quad*8];
      #pragma unroll
      for (int nt = 0; nt < 16; ++nt) {
        short8 b = *(const short8*)&W1abp[((kt*4 + quad) * 256 + nt*16 + l16) * 8];
        acc[nt] = __builtin_amdgcn_mfma_f32_16x16x32_bf16(a, b, acc[nt], 0, 0, 0);
      }
    }
    #pragma unroll
    for (int nt = 0; nt < 16; ++nt) {
      int col = nt*16 + l16;
      float bb = (col < 128) ? b1[col] : 0.f;
      #pragma unroll
      for (int r = 0; r < 4; ++r) {
        int row = base + quad*4 + r;
        if (row < N) {
          float v = acc[nt][r] + bb;
          if (col < 128) pa[(size_t)row * 128 + col]         = f2bf(v);
          else           pb[(size_t)row * 128 + (col - 128)] = f2bf(v);
        }
      }
    }
  }
}

// ---------------- edge kernel: table-gather + pipelined silu/segmented-sum ----------------
__global__ __launch_bounds__(256, 4) void k_edge(
    const short* __restrict__ pa, const short* __restrict__ pb,
    const short* __restrict__ tblL,
    const int2* __restrict__ sd_p, const int* __restrict__ de_p,
    float* __restrict__ S, int E)
{
  __shared__ __align__(16) int ses[TE], des[TE], tys[TE];

  const int tid  = threadIdx.x;
  const int lane = tid & 63;
  const int w    = tid >> 6;
  const int ebase = blockIdx.x * TE;

  if (tid < TE) {
    int ge = ebase + tid;
    if (ge < E) {
      int2 v = sd_p[ge];
      ses[tid] = v.x;
      tys[tid] = v.y;
      des[tid] = de_p[ge];
    } else {
      ses[tid] = 0; tys[tid] = 0; des[tid] = -1;
    }
  }
  __syncthreads();

  const int d2 = lane * 2;
  int prev_d = (w > 0) ? des[w*32 - 1] : ((ebase > 0) ? de_p[ebase - 1] : -1);
  int next_d = (w < 3) ? des[w*32 + 32] : ((ebase + TE < E) ? de_p[ebase + TE] : -1);

  unsigned ub[2][8], ue[2][8], pz[2][8];
  int      dd[2][8];

  auto loadg = [&](int buf, int g) {
    const int rowb = w*32 + g*8;
    int4 dA = *(const int4*)&des[rowb];
    int4 dB = *(const int4*)&des[rowb + 4];
    int4 sA = *(const int4*)&ses[rowb];
    int4 sB = *(const int4*)&ses[rowb + 4];
    int4 tA = *(const int4*)&tys[rowb];
    int4 tB = *(const int4*)&tys[rowb + 4];
    int dv[8] = {dA.x, dA.y, dA.z, dA.w, dB.x, dB.y, dB.z, dB.w};
    int sv[8] = {sA.x, sA.y, sA.z, sA.w, sB.x, sB.y, sB.z, sB.w};
    int tv[8] = {tA.x, tA.y, tA.z, tA.w, tB.x, tB.y, tB.z, tB.w};
    #pragma unroll
    for (int j = 0; j < 8; ++j) {
      int sn = __builtin_amdgcn_readfirstlane(sv[j]);
      int dn = __builtin_amdgcn_readfirstlane(dv[j]);
      int tn = __builtin_amdgcn_readfirstlane(tv[j]);
      dd[buf][j] = dn;
      ub[buf][j] = *(const unsigned*)&pb[(size_t)sn * 128 + d2];
      pz[buf][j] = (dn >= 0) ? *(const unsigned*)&pa[(size_t)dn * 128 + d2] : 0u;
      ue[buf][j] = *(const unsigned*)&tblL[(size_t)tn * 128 + d2];
    }
  };

  int   cur = -2;
  float s0 = 0.f, s1 = 0.f;
  float p0 = 0.f, p1 = 0.f;
  bool  openL = false;

  auto consume = [&](int buf, int g) {
    #pragma unroll
    for (int j = 0; j < 8; ++j) {
      int d = dd[buf][j];
      if (d != cur) {
        if (cur >= 0) {
          if (openL) {
            atomicAdd(&S[(size_t)cur * 128 + d2],     s0);
            atomicAdd(&S[(size_t)cur * 128 + d2 + 1], s1);
          } else {
            *(float2*)&S[(size_t)cur * 128 + d2] = make_float2(s0, s1);
          }
        }
        cur = d; s0 = 0.f; s1 = 0.f;
        openL = (g == 0) && (j == 0) && (prev_d == d);
        p0 = bflo(pz[buf][j]); p1 = bfhi(pz[buf][j]);
      }
      if (cur >= 0) {
        float x0 = p0 + bflo(ub[buf][j]) + bflo(ue[buf][j]);
        float x1 = p1 + bfhi(ub[buf][j]) + bfhi(ue[buf][j]);
        s0 += x0 * __builtin_amdgcn_rcpf(1.f + __expf(-x0));
        s1 += x1 * __builtin_amdgcn_rcpf(1.f + __expf(-x1));
      }
    }
  };

  loadg(0, 0);
  loadg(1, 1);
  consume(0, 0);
  loadg(0, 2);
  consume(1, 1);
  loadg(1, 3);
  consume(0, 2);
  consume(1, 3);

  if (cur >= 0) {
    bool openR = (next_d == cur);
    if (openL || openR) {
      atomicAdd(&S[(size_t)cur * 128 + d2],     s0);
      atomicAdd(&S[(size_t)cur * 128 + d2 + 1], s1);
    } else {
      *(float2*)&S[(size_t)cur * 128 + d2] = make_float2(s0, s1);
    }
  }
}

// ---------------- mean pool (batch_ids sorted): wave per 64 nodes ----------------
__global__ void k_pool(const float* __restrict__ h, const int* __restrict__ batch_ids,
                       float* __restrict__ pooled, float* __restrict__ counts, int N) {
  int lane = threadIdx.x & 63;
  int base = blockIdx.x * 64;
  float acc = 0.f;
  int   cnt = 0;
  int  gcur = -1;
  for (int n = 0; n < 64; ++n) {
    int node = base + n;
    if (node >= N) break;
    int g = batch_ids[node];
    if (g != gcur) {
      if (gcur >= 0) {
        atomicAdd(&pooled[gcur * NODE_DIM + lane], acc);
        if (lane == 0) atomicAdd(&counts[gcur], (float)cnt);
      }
      gcur = g; acc = 0.f; cnt = 0;
    }
    acc += h[(size_t)node * NODE_DIM + lane];
    cnt++;
  }
  if (gcur >= 0) {
    atomicAdd(&pooled[gcur * NODE_DIM + lane], acc);
    if (lane == 0) atomicAdd(&counts[gcur], (float)cnt);
  }
}

__global__ void k_final(const float* __restrict__ pooled, const float* __restrict__ counts,
                        const float* __restrict__ fc_w, const float* __restrict__ fc_b,
                        float* __restrict__ out, int G) {
  int g = blockIdx.x * blockDim.x + threadIdx.x;
  if (g < G) {
    float acc = 0.f;
    for (int d = 0; d < NODE_DIM; ++d) acc += pooled[g * NODE_DIM + d] * fc_w[d];
    float c = counts[g];
    if (c < 1.f) c = 1.f;
    out[g] = acc / c + fc_b[0];
  }
}

extern "C" void kernel_launch(void* const* d_in, const int* in_sizes, int n_in,
                              void* d_out, int out_size, void* d_ws, size_t ws_size,
                              hipStream_t stream) {
  const int*   atoms   = (const int*)  d_in[0];
  const int*   eidx    = (const int*)  d_in[1];
  const float* coords  = (const float*)d_in[2];
  const int*   isr     = (const int*)  d_in[3];
  const int*   batch   = (const int*)  d_in[4];
  const float* embed_w = (const float*)d_in[5];
  const float* sub_w   = (const float*)d_in[6];
  const float* W1      = (const float*)d_in[7];
  const float* b1      = (const float*)d_in[8];
  const float* W2      = (const float*)d_in[9];
  const float* b2      = (const float*)d_in[10];
  const float* fc_w    = (const float*)d_in[11];
  const float* fc_b    = (const float*)d_in[12];
  float* out = (float*)d_out;

  const int N = in_sizes[0];
  const int E = in_sizes[1] / 2;
  const int L = in_sizes[8] / HIDDEN;
  const int G = out_size;

  const int* srcv = eidx;
  const int* dstv = eidx + E;

  size_t off = 0;
  auto carve = [&](size_t bytes) -> char* {
    char* p = (char*)d_ws + off;
    off += (bytes + 255) & ~(size_t)255;
    return p;
  };
  float* hf     = (float*)carve((size_t)N * NODE_DIM * 4);
  short* hb     = (short*)carve((size_t)N * NODE_DIM * 2);
  float* S      = (float*)carve((size_t)N * HIDDEN * 4);
  short* pa     = (short*)carve((size_t)N * HIDDEN * 2);
  short* pb     = (short*)carve((size_t)N * HIDDEN * 2);
  int*   ety    = (int*)  carve((size_t)E * 4);
  int*   cnts   = (int*)  carve((size_t)N * 4);
  int*   cursor = (int*)  carve((size_t)N * 4);
  int*   bn     = (int*)  carve((size_t)N * 4);
  int*   bn_cnt = (int*)  carve(256);
  int2*  sd_p   = (int2*) carve((size_t)E * 8);
  int*   de_p   = (int*)  carve((size_t)E * 4);
  int*   part   = (int*)  carve(((size_t)N / 256 + 2) * 4);
  short* W1abp  = (short*)carve((size_t)L * L1ABSZ * 2);
  short* W2p    = (short*)carve((size_t)L * L2SZ * 2);
  short* tbl    = (short*)carve((size_t)L * TBLSZ * 2);
  float* pooled = (float*)carve((size_t)G * NODE_DIM * 4);
  float* cntg   = (float*)carve((size_t)G * 4);

  const int nbN = (N + 255) / 256;

  k_init<<<1024, 256, 0, stream>>>(atoms, embed_w, hf, hb, N * NODE_DIM);
  k_zero4<<<2048, 256, 0, stream>>>((float4*)S, N * HIDDEN / 4);
  k_edge_pre<<<1024, 256, 0, stream>>>(srcv, dstv, coords, isr, ety, E);
  k_zero_i<<<nbN, 256, 0, stream>>>(cnts, N);
  k_zero_f<<<(G * NODE_DIM + G + 255) / 256, 256, 0, stream>>>(pooled, G * NODE_DIM + G);
  k_hist<<<1024, 256, 0, stream>>>(dstv, cnts, E);
  k_scan_part<<<nbN, 256, 0, stream>>>(cnts, part, N);
  k_scan_top<<<1, 512, 0, stream>>>(part, nbN, bn_cnt);
  k_scan_apply<<<nbN, 256, 0, stream>>>(cnts, part, cursor, bn, bn_cnt, N);
  k_build<<<1024, 256, 0, stream>>>(srcv, dstv, ety, cursor, sd_p, de_p, E);
  k_pack_w1ab<<<(L * L1ABSZ + 255) / 256, 256, 0, stream>>>(W1, W1abp, L * L1ABSZ);
  k_pack_w2<<<(L * L2SZ + 255) / 256, 256, 0, stream>>>(W2, W2p, L * L2SZ);
  k_tbl<<<(L * 2 * TBL_BINS + 255) / 256, 256, 0, stream>>>(W1, sub_w, tbl, L * 2 * TBL_BINS);

  const int nblk_n = (N + 63) / 64;
  const int nblk_e = (E + TE - 1) / TE;
  for (int l = 0; l < L; ++l) {
    k_node<<<nblk_n, 256, 0, stream>>>(
        hf, hb, S, cnts,
        (l > 0) ? W2p + (size_t)(l - 1) * L2SZ : (const short*)nullptr,
        (l > 0) ? b2 + (size_t)(l - 1) * NODE_DIM : (const float*)nullptr,
        W1abp + (size_t)l * L1ABSZ, b1 + (size_t)l * HIDDEN,
        pa, pb, N);
    if (l > 0)
      k_zrows<<<256, 256, 0, stream>>>(S, bn, bn_cnt);
    k_edge<<<nblk_e, 256, 0, stream>>>(pa, pb, tbl + (size_t)l * TBLSZ,
                                       sd_p, de_p, S, E);
  }
  k_node<<<nblk_n, 256, 0, stream>>>(
      hf, hb, S, cnts,
      W2p + (size_t)(L - 1) * L2SZ, b2 + (size_t)(L - 1) * NODE_DIM,
      (const short*)nullptr, (const float*)nullptr, pa, pb, N);

  k_pool<<<(N + 63) / 64, 64, 0, stream>>>(hf, batch, pooled, cntg, N);
  k_final<<<1, 64, 0, stream>>>(pooled, cntg, fc_w, fc_b, out, G);
}